// Round 14
// baseline (424.813 us; speedup 1.0000x reference)
//
#include <hip/hip_runtime.h>

static constexpr int FC = 128;

typedef __attribute__((ext_vector_type(8))) __bf16 bf16x8;
typedef __attribute__((ext_vector_type(4))) float f32x4;

__device__ __forceinline__ unsigned short f2bf(float f) {
  unsigned u = __float_as_uint(f);
  unsigned r = (u + 0x7FFF + ((u >> 16) & 1)) >> 16;
  return (unsigned short)r;
}
__device__ __forceinline__ float bf2f(unsigned short h) {
  return __uint_as_float((unsigned)h << 16);
}
__device__ __forceinline__ unsigned pk_i8x4(int q0, int q1, int q2, int q3) {
  return (unsigned)(q0 & 0xff) | ((unsigned)(q1 & 0xff) << 8) |
         ((unsigned)(q2 & 0xff) << 16) | ((unsigned)(q3 & 0xff) << 24);
}

// ---------------- zero deg + stats + smax ----------------
__global__ __launch_bounds__(256) void zero_kernel(int* __restrict__ deg,
                                                   float* __restrict__ stats,
                                                   unsigned* __restrict__ smax, int n) {
  int i = blockIdx.x * 256 + threadIdx.x;
  if (i < n) deg[i] = 0;
  if (i < 768) stats[i] = 0.f;
  if (i < 4) smax[i] = 0u;
}

// ---------------- fused pre-pass: edge count | x->bf16+absmax | W packs ----------------
// blocks [0,cb): count+rank. [cb,cb+xb): x->bf16, tensor absmax. [.. +48): W. [.. +4): head W.
__global__ __launch_bounds__(256) void pre_kernel(
    const int* __restrict__ dst, int* __restrict__ deg, int* __restrict__ rank, int e,
    const float* __restrict__ x, const float* __restrict__ w1l, const float* __restrict__ w1r,
    const float* __restrict__ w2l, const float* __restrict__ w2r,
    const float* __restrict__ w3l, const float* __restrict__ w3r,
    const float* __restrict__ wh,
    unsigned short* __restrict__ x_bf, unsigned* __restrict__ smax,
    unsigned short* __restrict__ wc1,
    unsigned short* __restrict__ wc2, unsigned short* __restrict__ wc3,
    unsigned short* __restrict__ whb, int nx8, int cb, int xb) {
  int b = blockIdx.x;
  int t = threadIdx.x;
  if (b < cb) {
    int i = b * 256 + t;
    if (i < e) rank[i] = atomicAdd(&deg[dst[i]], 1);
    return;
  }
  int r = b - cb;
  if (r < xb) {
    int i = r * 256 + t;
    float m = 0.f;
    if (i < nx8) {
      const float* p = x + (size_t)i * 8;
      float4 a = *reinterpret_cast<const float4*>(p);
      float4 c = *reinterpret_cast<const float4*>(p + 4);
      ushort4 o0 = {f2bf(a.x), f2bf(a.y), f2bf(a.z), f2bf(a.w)};
      ushort4 o1 = {f2bf(c.x), f2bf(c.y), f2bf(c.z), f2bf(c.w)};
      unsigned short* q = x_bf + (size_t)i * 8;
      *reinterpret_cast<ushort4*>(q) = o0;
      *reinterpret_cast<ushort4*>(q + 4) = o1;
      m = fmaxf(fmaxf(fmaxf(fabsf(a.x), fabsf(a.y)), fmaxf(fabsf(a.z), fabsf(a.w))),
                fmaxf(fmaxf(fabsf(c.x), fabsf(c.y)), fmaxf(fabsf(c.z), fabsf(c.w))));
    }
    m = fmaxf(m, __shfl_xor(m, 1));
    m = fmaxf(m, __shfl_xor(m, 2));
    m = fmaxf(m, __shfl_xor(m, 4));
    m = fmaxf(m, __shfl_xor(m, 8));
    m = fmaxf(m, __shfl_xor(m, 16));
    m = fmaxf(m, __shfl_xor(m, 32));
    if ((t & 63) == 0) atomicMax(&smax[0], __float_as_uint(m));
    return;
  }
  r -= xb;
  if (r < 48) {
    int layer = r >> 4;
    const float* wl = layer == 0 ? w1l : (layer == 1 ? w2l : w3l);
    const float* wr = layer == 0 ? w1r : (layer == 1 ? w2r : w3r);
    unsigned short* out = layer == 0 ? wc1 : (layer == 1 ? wc2 : wc3);
    int i = (r & 15) * 256 + t;
    int row = i >> 5;
    int k8 = (i & 31) * 8;
    const float* src = (k8 < 128) ? (wl + (size_t)row * 128 + k8)
                                  : (wr + (size_t)row * 128 + (k8 - 128));
    float4 a = *reinterpret_cast<const float4*>(src);
    float4 c = *reinterpret_cast<const float4*>(src + 4);
    ushort4 o0 = {f2bf(a.x), f2bf(a.y), f2bf(a.z), f2bf(a.w)};
    ushort4 o1 = {f2bf(c.x), f2bf(c.y), f2bf(c.z), f2bf(c.w)};
    unsigned short* q = out + (size_t)row * 256 + k8;
    *reinterpret_cast<ushort4*>(q) = o0;
    *reinterpret_cast<ushort4*>(q + 4) = o1;
  } else {
    int i = (r - 48) * 256 + t;
    const float* p = wh + (size_t)i * 8;
    float4 a = *reinterpret_cast<const float4*>(p);
    float4 c = *reinterpret_cast<const float4*>(p + 4);
    ushort4 o0 = {f2bf(a.x), f2bf(a.y), f2bf(a.z), f2bf(a.w)};
    ushort4 o1 = {f2bf(c.x), f2bf(c.y), f2bf(c.z), f2bf(c.w)};
    unsigned short* q = whb + (size_t)i * 8;
    *reinterpret_cast<ushort4*>(q) = o0;
    *reinterpret_cast<ushort4*>(q + 4) = o1;
  }
}

// ---------------- quantize bf16 rows -> int8 table with tensor scale ----------------
__global__ __launch_bounds__(256) void quant_kernel(const unsigned short* __restrict__ hbf,
                                                    const unsigned* __restrict__ smax,
                                                    unsigned* __restrict__ tab, int n16) {
  int i = blockIdx.x * 256 + threadIdx.x;
  if (i >= n16) return;
  float mx = __uint_as_float(*smax);
  float qi = 127.0f / fmaxf(mx, 1e-30f);
  const unsigned short* p = hbf + (size_t)i * 8;
  ushort4 v0 = *reinterpret_cast<const ushort4*>(p);
  ushort4 v1 = *reinterpret_cast<const ushort4*>(p + 4);
  int q0 = (int)rintf(bf2f(v0.x) * qi), q1 = (int)rintf(bf2f(v0.y) * qi);
  int q2 = (int)rintf(bf2f(v0.z) * qi), q3 = (int)rintf(bf2f(v0.w) * qi);
  int q4 = (int)rintf(bf2f(v1.x) * qi), q5 = (int)rintf(bf2f(v1.y) * qi);
  int q6 = (int)rintf(bf2f(v1.z) * qi), q7 = (int)rintf(bf2f(v1.w) * qi);
  uint2 u = {pk_i8x4(q0, q1, q2, q3), pk_i8x4(q4, q5, q6, q7)};
  *reinterpret_cast<uint2*>(tab + (size_t)i * 2) = u;
}

// ---------------- CSR scans + fill ----------------
__global__ __launch_bounds__(256) void scan1_kernel(const int* __restrict__ deg,
                                                    int* __restrict__ bsum, int n) {
  int i = blockIdx.x * 256 + threadIdx.x;
  int v = (i < n) ? deg[i] : 0;
  __shared__ int ls[256];
  ls[threadIdx.x] = v;
  __syncthreads();
  for (int d = 128; d > 0; d >>= 1) {
    if (threadIdx.x < (unsigned)d) ls[threadIdx.x] += ls[threadIdx.x + d];
    __syncthreads();
  }
  if (threadIdx.x == 0) bsum[blockIdx.x] = ls[0];
}

__global__ __launch_bounds__(256) void scan23_kernel(const int* __restrict__ deg,
                                                     const int* __restrict__ bsum,
                                                     int* __restrict__ off, int n, int nb) {
  __shared__ int bls[256];
  __shared__ int ls[256];
  int t = threadIdx.x;
  int bv = (t < nb) ? bsum[t] : 0;
  bls[t] = bv;
  __syncthreads();
  for (int d = 1; d < 256; d <<= 1) {
    int u = (t >= d) ? bls[t - d] : 0;
    __syncthreads();
    bls[t] += u;
    __syncthreads();
  }
  int i = blockIdx.x * 256 + t;
  int v = (i < n) ? deg[i] : 0;
  ls[t] = v;
  __syncthreads();
  for (int d = 1; d < 256; d <<= 1) {
    int u = (t >= d) ? ls[t - d] : 0;
    __syncthreads();
    ls[t] += u;
    __syncthreads();
  }
  int base = blockIdx.x ? bls[blockIdx.x - 1] : 0;
  if (i < n) off[i] = base + ls[t] - v;
  if (blockIdx.x == 0 && t == 0) off[n] = bls[nb - 1];
}

__global__ void fill_kernel(const int* __restrict__ src, const int* __restrict__ dst,
                            const int* __restrict__ rank, const int* __restrict__ off,
                            int* __restrict__ csr, int e) {
  int i = blockIdx.x * blockDim.x + threadIdx.x;
  if (i < e) csr[off[dst[i]] + rank[i]] = src[i];
}

// ---------------- mean aggregation: int8 rows, uniform tensor scale, BN+ReLU on read ----------------
// tab: [n][32] uints. agg out: bf16 [n][128]. One half-wave (32 lanes) per node.
template <bool BNIN>
__global__ __launch_bounds__(256) void aggregate_kernel(const unsigned* __restrict__ tab,
                                                        const unsigned* __restrict__ smax,
                                                        const int* __restrict__ off,
                                                        const int* __restrict__ csr,
                                                        unsigned short* __restrict__ agg,
                                                        const float* __restrict__ stats,
                                                        const float* __restrict__ g,
                                                        const float* __restrict__ be,
                                                        float invn, int n) {
  int hw = (int)((blockIdx.x * blockDim.x + threadIdx.x) >> 5);
  int lane = threadIdx.x & 31;
  if (hw >= n) return;

  float sdeq = __uint_as_float(*smax) * (1.0f / 127.0f);   // uniform dequant scale

  float sc0 = sdeq, sc1 = sdeq, sc2 = sdeq, sc3 = sdeq;    // per-channel (q -> value) scale
  float sh0 = 0.f, sh1 = 0.f, sh2 = 0.f, sh3 = 0.f;
  if (BNIN) {
    int c0 = lane * 4;
    float4 s  = *reinterpret_cast<const float4*>(stats + c0);
    float4 s2 = *reinterpret_cast<const float4*>(stats + 128 + c0);
    float4 gv = *reinterpret_cast<const float4*>(g + c0);
    float4 bv = *reinterpret_cast<const float4*>(be + c0);
    float m0 = s.x * invn, m1 = s.y * invn, m2 = s.z * invn, m3 = s.w * invn;
    float b0 = gv.x * rsqrtf(fmaxf(s2.x * invn - m0 * m0, 0.f) + 1e-5f);
    float b1 = gv.y * rsqrtf(fmaxf(s2.y * invn - m1 * m1, 0.f) + 1e-5f);
    float b2 = gv.z * rsqrtf(fmaxf(s2.z * invn - m2 * m2, 0.f) + 1e-5f);
    float b3 = gv.w * rsqrtf(fmaxf(s2.w * invn - m3 * m3, 0.f) + 1e-5f);
    sh0 = bv.x - m0 * b0; sh1 = bv.y - m1 * b1;
    sh2 = bv.z - m2 * b2; sh3 = bv.w - m3 * b3;
    sc0 = b0 * sdeq; sc1 = b1 * sdeq; sc2 = b2 * sdeq; sc3 = b3 * sdeq;
  }

  int s0 = off[hw], s1 = off[hw + 1];
  float a0 = 0.f, a1 = 0.f, a2 = 0.f, a3 = 0.f;

#define ACCV(u)                                                   \
  {                                                               \
    float q0 = (float)(((int)(u) << 24) >> 24);                   \
    float q1 = (float)(((int)(u) << 16) >> 24);                   \
    float q2 = (float)(((int)(u) << 8) >> 24);                    \
    float q3 = (float)((int)(u) >> 24);                           \
    if (BNIN) {                                                   \
      a0 += fmaxf(fmaf(q0, sc0, sh0), 0.f);                       \
      a1 += fmaxf(fmaf(q1, sc1, sh1), 0.f);                       \
      a2 += fmaxf(fmaf(q2, sc2, sh2), 0.f);                       \
      a3 += fmaxf(fmaf(q3, sc3, sh3), 0.f);                       \
    } else {                                                      \
      a0 += q0; a1 += q1; a2 += q2; a3 += q3;                     \
    }                                                             \
  }

  int j = s0;
  for (; j + 8 <= s1; j += 8) {
    int i0 = csr[j],     i1 = csr[j + 1], i2 = csr[j + 2], i3 = csr[j + 3];
    int i4 = csr[j + 4], i5 = csr[j + 5], i6 = csr[j + 6], i7 = csr[j + 7];
    unsigned u0 = tab[(size_t)i0 * 32 + lane];
    unsigned u1 = tab[(size_t)i1 * 32 + lane];
    unsigned u2 = tab[(size_t)i2 * 32 + lane];
    unsigned u3 = tab[(size_t)i3 * 32 + lane];
    unsigned u4 = tab[(size_t)i4 * 32 + lane];
    unsigned u5 = tab[(size_t)i5 * 32 + lane];
    unsigned u6 = tab[(size_t)i6 * 32 + lane];
    unsigned u7 = tab[(size_t)i7 * 32 + lane];
    ACCV(u0) ACCV(u1) ACCV(u2) ACCV(u3) ACCV(u4) ACCV(u5) ACCV(u6) ACCV(u7)
  }
  for (; j < s1; j++) {
    unsigned u0 = tab[(size_t)csr[j] * 32 + lane];
    ACCV(u0)
  }
#undef ACCV

  int d = s1 - s0;
  float inv = 1.0f / (float)(d > 0 ? d : 1);
  if (!BNIN) inv *= sdeq;   // fold uniform dequant into the mean for the raw path
  ushort4 o = {f2bf(a0 * inv), f2bf(a1 * inv), f2bf(a2 * inv), f2bf(a3 * inv)};
  *reinterpret_cast<ushort4*>(agg + (size_t)hw * FC + lane * 4) = o;
}

// ---------------- MFMA GEMM: W in LDS (XOR-swizzled), A preloaded ----------------
// SMAX: atomically accumulate tensor absmax of (pre-BN) outputs into smaxOut.
template <int NCOLS, int KTOT, bool DUAL, bool OUT_BF, bool STATS, bool BNIN, bool SMAX>
__global__ __launch_bounds__(256) void gemm_kernel(const unsigned short* __restrict__ A1,
                                                   const unsigned short* __restrict__ A2,
                                                   const unsigned short* __restrict__ W,
                                                   const float* __restrict__ bias,
                                                   void* __restrict__ Cout,
                                                   unsigned* __restrict__ smaxOut,
                                                   float* __restrict__ statsOut,
                                                   const float* __restrict__ statsIn,
                                                   const float* __restrict__ g,
                                                   const float* __restrict__ be,
                                                   float invn, int nrows) {
  constexpr int NKT = KTOT / 32;
  constexpr int NCF = NCOLS / 16;
  constexpr int RB = KTOT * 2;
  constexpr int WBYTES = NCOLS * KTOT * 2;
  __shared__ __align__(16) unsigned char Wl[WBYTES];
  __shared__ float scv[128], shv[128];

  int t = threadIdx.x;

  {
    constexpr int CH = WBYTES / 16 / 256;
#pragma unroll
    for (int c = 0; c < CH; c++) {
      int byte = (c * 256 + t) * 16;
      int row = byte / RB;
      int cb = byte % RB;
      float4 v = *reinterpret_cast<const float4*>(reinterpret_cast<const char*>(W) + byte);
      *reinterpret_cast<float4*>(Wl + row * RB + (cb ^ ((row & 7) << 4))) = v;
    }
  }

  if (BNIN && t < 128) {
    float mean = statsIn[t] * invn;
    float var = fmaxf(statsIn[128 + t] * invn - mean * mean, 0.f);
    float s = g[t] * rsqrtf(var + 1e-5f);
    scv[t] = s;
    shv[t] = be[t] - mean * s;
  }

  int w = t >> 6;
  int l = t & 63;
  int lm = l & 15;
  int hi = l >> 4;
  int lk = hi * 8;
  int row = blockIdx.x * 64 + w * 16 + lm;
  int rclamp = min(row, nrows - 1);

  bf16x8 a[NKT];
#pragma unroll
  for (int kt = 0; kt < NKT; kt++) {
    const unsigned short* Ap;
    int kk;
    if (!DUAL || kt < NKT / 2) { Ap = A1; kk = kt * 32; }
    else                       { Ap = A2; kk = (kt - NKT / 2) * 32; }
    a[kt] = *reinterpret_cast<const bf16x8*>(Ap + (size_t)rclamp * 128 + kk + lk);
  }

  f32x4 acc[NCF];
#pragma unroll
  for (int cf = 0; cf < NCF; cf++) acc[cf] = {0.f, 0.f, 0.f, 0.f};

  __syncthreads();

  if (BNIN) {
#pragma unroll
    for (int kt = 0; kt < NKT; kt++) {
      if (!DUAL || kt >= NKT / 2) {
        int ch0 = (DUAL ? (kt - NKT / 2) : kt) * 32 + lk;
#pragma unroll
        for (int j = 0; j < 8; j++) {
          float v = (float)a[kt][j];
          v = fmaxf(fmaf(v, scv[ch0 + j], shv[ch0 + j]), 0.f);
          a[kt][j] = (__bf16)v;
        }
      }
    }
  }

#pragma unroll
  for (int kt = 0; kt < NKT; kt++) {
#pragma unroll
    for (int cf = 0; cf < NCF; cf++) {
      int r = cf * 16 + lm;
      int cb = kt * 64 + hi * 16;
      bf16x8 b = *reinterpret_cast<const bf16x8*>(Wl + r * RB + (cb ^ ((r & 7) << 4)));
      acc[cf] = __builtin_amdgcn_mfma_f32_16x16x32_bf16(a[kt], b, acc[cf], 0, 0, 0);
    }
  }

  // fold bias
#pragma unroll
  for (int cf = 0; cf < NCF; cf++) {
    float bs = bias[cf * 16 + lm];
#pragma unroll
    for (int r = 0; r < 4; r++) acc[cf][r] += bs;
  }

  if (SMAX) {
    float m = 0.f;
#pragma unroll
    for (int cf = 0; cf < NCF; cf++)
#pragma unroll
      for (int r = 0; r < 4; r++) m = fmaxf(m, fabsf(acc[cf][r]));
    m = fmaxf(m, __shfl_xor(m, 1));
    m = fmaxf(m, __shfl_xor(m, 2));
    m = fmaxf(m, __shfl_xor(m, 4));
    m = fmaxf(m, __shfl_xor(m, 8));
    m = fmaxf(m, __shfl_xor(m, 16));
    m = fmaxf(m, __shfl_xor(m, 32));
    if (l == 0) atomicMax(smaxOut, __float_as_uint(m));
  }

  __shared__ float wsum[4][NCOLS];
  __shared__ float wsq[4][NCOLS];

  int orow0 = blockIdx.x * 64 + w * 16 + hi * 4;
#pragma unroll
  for (int cf = 0; cf < NCF; cf++) {
    int col = cf * 16 + lm;
    float s = 0.f, s2 = 0.f;
#pragma unroll
    for (int r = 0; r < 4; r++) {
      int orow = orow0 + r;
      bool ok = orow < nrows;
      float v = acc[cf][r];
      if (ok) {
        if (OUT_BF)
          ((unsigned short*)Cout)[(size_t)orow * NCOLS + col] = f2bf(v);
        else
          ((float*)Cout)[(size_t)orow * NCOLS + col] = v;
      }
      if (STATS) {
        float vv = ok ? v : 0.f;
        s += vv; s2 += vv * vv;
      }
    }
    if (STATS) {
      s  += __shfl_xor(s, 16);  s  += __shfl_xor(s, 32);
      s2 += __shfl_xor(s2, 16); s2 += __shfl_xor(s2, 32);
      if (l < 16) { wsum[w][col] = s; wsq[w][col] = s2; }
    }
  }
  if (STATS) {
    __syncthreads();
    if (t < NCOLS) {
      atomicAdd(&statsOut[t], wsum[0][t] + wsum[1][t] + wsum[2][t] + wsum[3][t]);
    } else if (t < 2 * NCOLS) {
      int c = t - NCOLS;
      atomicAdd(&statsOut[t], wsq[0][c] + wsq[1][c] + wsq[2][c] + wsq[3][c]);
    }
  }
}

// ---------------- launch ----------------
extern "C" void kernel_launch(void* const* d_in, const int* in_sizes, int n_in,
                              void* d_out, int out_size, void* d_ws, size_t ws_size,
                              hipStream_t stream) {
  const float* x   = (const float*)d_in[0];
  const int*   ei  = (const int*)d_in[1];
  const float* w1l = (const float*)d_in[2];
  const float* w1r = (const float*)d_in[3];
  const float* b1c = (const float*)d_in[4];
  const float* w2l = (const float*)d_in[5];
  const float* w2r = (const float*)d_in[6];
  const float* b2c = (const float*)d_in[7];
  const float* w3l = (const float*)d_in[8];
  const float* w3r = (const float*)d_in[9];
  const float* b3c = (const float*)d_in[10];
  const float* g1  = (const float*)d_in[11];
  const float* be1 = (const float*)d_in[12];
  const float* g2  = (const float*)d_in[13];
  const float* be2 = (const float*)d_in[14];
  const float* g3  = (const float*)d_in[15];
  const float* be3 = (const float*)d_in[16];
  const float* wh  = (const float*)d_in[17];
  const float* bh  = (const float*)d_in[18];

  int n = in_sizes[0] / FC;
  int e = in_sizes[1] / 2;
  const int* srcI = ei;
  const int* dstI = ei + e;

  char* p = (char*)d_ws;
  auto take = [&](size_t bytes) {
    char* q = p;
    p += (bytes + 255) & ~(size_t)255;
    return q;
  };
  int nb = (n + 255) / 256;
  int* deg  = (int*)take((size_t)n * 4);
  int* off  = (int*)take((size_t)(n + 1) * 4);
  int* bsum = (int*)take((size_t)nb * 4);
  int* rank = (int*)take((size_t)e * 4);
  int* csr  = (int*)take((size_t)e * 4);
  unsigned short* x_bf = (unsigned short*)take((size_t)n * FC * 2);
  unsigned short* agg  = (unsigned short*)take((size_t)n * FC * 2);
  unsigned short* h1   = (unsigned short*)take((size_t)n * FC * 2);
  unsigned short* h2   = (unsigned short*)take((size_t)n * FC * 2);
  unsigned char*  ai8  = (unsigned char*)take((size_t)n * FC);   // int8 gather table (reused)
  unsigned short* wc1  = (unsigned short*)take(128 * 256 * 2);
  unsigned short* wc2  = (unsigned short*)take(128 * 256 * 2);
  unsigned short* wc3  = (unsigned short*)take(128 * 256 * 2);
  unsigned short* whb  = (unsigned short*)take(64 * 128 * 2);
  float*    stats = (float*)take(3 * 256 * 4);
  unsigned* smax  = (unsigned*)take(4 * 4);   // [0]=x, [1]=h1, [2]=h2

  float invn = 1.0f / (float)n;
  int nx8 = n * 16;
  int cb = (e + 255) / 256;
  int xb = (nx8 + 255) / 256;

  zero_kernel<<<nb, 256, 0, stream>>>(deg, stats, smax, n);
  pre_kernel<<<cb + xb + 52, 256, 0, stream>>>(dstI, deg, rank, e,
                                               x, w1l, w1r, w2l, w2r, w3l, w3r, wh,
                                               x_bf, smax, wc1, wc2, wc3, whb, nx8, cb, xb);

  scan1_kernel<<<nb, 256, 0, stream>>>(deg, bsum, n);
  scan23_kernel<<<nb, 256, 0, stream>>>(deg, bsum, off, n, nb);
  fill_kernel<<<cb, 256, 0, stream>>>(srcI, dstI, rank, off, csr, e);
  quant_kernel<<<xb, 256, 0, stream>>>(x_bf, smax, (unsigned*)ai8, nx8);

  int gb = (n + 63) / 64;
  int ab = (n + 7) / 8;

  // layer 1: gather int8(x); root = bf16 x; smax[1] for h1
  aggregate_kernel<false><<<ab, 256, 0, stream>>>((const unsigned*)ai8, smax, off, csr, agg,
                                                  nullptr, nullptr, nullptr, invn, n);
  gemm_kernel<128, 256, true, true, true, false, true><<<gb, 256, 0, stream>>>(
      agg, x_bf, wc1, b1c, h1, smax + 1, stats, nullptr, nullptr, nullptr, invn, n);
  quant_kernel<<<xb, 256, 0, stream>>>(h1, smax + 1, (unsigned*)ai8, nx8);

  // layer 2: gather int8(h1) with BN1 on read; root = bf16 h1 (BN1 in gemm); smax[2] for h2
  aggregate_kernel<true><<<ab, 256, 0, stream>>>((const unsigned*)ai8, smax + 1, off, csr, agg,
                                                 stats, g1, be1, invn, n);
  gemm_kernel<128, 256, true, true, true, true, true><<<gb, 256, 0, stream>>>(
      agg, h1, wc2, b2c, h2, smax + 2, stats + 256, stats, g1, be1, invn, n);
  quant_kernel<<<xb, 256, 0, stream>>>(h2, smax + 2, (unsigned*)ai8, nx8);

  // layer 3: gather int8(h2) with BN2 on read; no smax needed
  aggregate_kernel<true><<<ab, 256, 0, stream>>>((const unsigned*)ai8, smax + 2, off, csr, agg,
                                                 stats + 256, g2, be2, invn, n);
  gemm_kernel<128, 256, true, true, true, true, false><<<gb, 256, 0, stream>>>(
      agg, h2, wc3, b3c, h1, nullptr, stats + 512, stats + 256, g2, be2, invn, n);

  // head: BN3 on read of h1
  gemm_kernel<64, 128, false, false, false, true, false><<<gb, 256, 0, stream>>>(
      h1, nullptr, whb, bh, d_out, nullptr, nullptr, stats + 512, g3, be3, invn, n);
}

// Round 15
// 276.404 us; speedup vs baseline: 1.5369x; 1.5369x over previous
//
#include <hip/hip_runtime.h>

static constexpr int FC = 128;

typedef __attribute__((ext_vector_type(8))) __bf16 bf16x8;
typedef __attribute__((ext_vector_type(4))) float f32x4;

__device__ __forceinline__ unsigned short f2bf(float f) {
  unsigned u = __float_as_uint(f);
  unsigned r = (u + 0x7FFF + ((u >> 16) & 1)) >> 16;
  return (unsigned short)r;
}
__device__ __forceinline__ float bf2f(unsigned short h) {
  return __uint_as_float((unsigned)h << 16);
}
__device__ __forceinline__ unsigned pk_i8x4(int q0, int q1, int q2, int q3) {
  return (unsigned)(q0 & 0xff) | ((unsigned)(q1 & 0xff) << 8) |
         ((unsigned)(q2 & 0xff) << 16) | ((unsigned)(q3 & 0xff) << 24);
}

// ---------------- zero deg + stats + smax ----------------
__global__ __launch_bounds__(256) void zero_kernel(int* __restrict__ deg,
                                                   float* __restrict__ stats,
                                                   float* __restrict__ smax, int n) {
  int i = blockIdx.x * 256 + threadIdx.x;
  if (i < n) deg[i] = 0;
  if (i < 768) stats[i] = 0.f;
  if (i < 4) smax[i] = 0.f;
}

// ---------------- conversions: x->bf16 (+per-block max, NO atomics), W packs ----------------
// blocks [0,xb): x. [xb,xb+48): layer W. [xb+48,xb+52): head W.
__global__ __launch_bounds__(256) void convert_kernel(
    const float* __restrict__ x, const float* __restrict__ w1l, const float* __restrict__ w1r,
    const float* __restrict__ w2l, const float* __restrict__ w2r,
    const float* __restrict__ w3l, const float* __restrict__ w3r,
    const float* __restrict__ wh,
    unsigned short* __restrict__ x_bf, float* __restrict__ pmax,
    unsigned short* __restrict__ wc1,
    unsigned short* __restrict__ wc2, unsigned short* __restrict__ wc3,
    unsigned short* __restrict__ whb, int nx8, int xb) {
  int b = blockIdx.x;
  int t = threadIdx.x;
  if (b < xb) {
    int i = b * 256 + t;
    float m = 0.f;
    if (i < nx8) {
      const float* p = x + (size_t)i * 8;
      float4 a = *reinterpret_cast<const float4*>(p);
      float4 c = *reinterpret_cast<const float4*>(p + 4);
      ushort4 o0 = {f2bf(a.x), f2bf(a.y), f2bf(a.z), f2bf(a.w)};
      ushort4 o1 = {f2bf(c.x), f2bf(c.y), f2bf(c.z), f2bf(c.w)};
      unsigned short* q = x_bf + (size_t)i * 8;
      *reinterpret_cast<ushort4*>(q) = o0;
      *reinterpret_cast<ushort4*>(q + 4) = o1;
      m = fmaxf(fmaxf(fmaxf(fabsf(a.x), fabsf(a.y)), fmaxf(fabsf(a.z), fabsf(a.w))),
                fmaxf(fmaxf(fabsf(c.x), fabsf(c.y)), fmaxf(fabsf(c.z), fabsf(c.w))));
    }
    __shared__ float red[256];
    red[t] = m;
    __syncthreads();
    for (int d = 128; d > 0; d >>= 1) {
      if (t < d) red[t] = fmaxf(red[t], red[t + d]);
      __syncthreads();
    }
    if (t == 0) pmax[b] = red[0];
    return;
  }
  int r = b - xb;
  if (r < 48) {
    int layer = r >> 4;
    const float* wl = layer == 0 ? w1l : (layer == 1 ? w2l : w3l);
    const float* wr = layer == 0 ? w1r : (layer == 1 ? w2r : w3r);
    unsigned short* out = layer == 0 ? wc1 : (layer == 1 ? wc2 : wc3);
    int i = (r & 15) * 256 + t;
    int row = i >> 5;
    int k8 = (i & 31) * 8;
    const float* src = (k8 < 128) ? (wl + (size_t)row * 128 + k8)
                                  : (wr + (size_t)row * 128 + (k8 - 128));
    float4 a = *reinterpret_cast<const float4*>(src);
    float4 c = *reinterpret_cast<const float4*>(src + 4);
    ushort4 o0 = {f2bf(a.x), f2bf(a.y), f2bf(a.z), f2bf(a.w)};
    ushort4 o1 = {f2bf(c.x), f2bf(c.y), f2bf(c.z), f2bf(c.w)};
    unsigned short* q = out + (size_t)row * 256 + k8;
    *reinterpret_cast<ushort4*>(q) = o0;
    *reinterpret_cast<ushort4*>(q + 4) = o1;
  } else {
    int i = (r - 48) * 256 + t;
    const float* p = wh + (size_t)i * 8;
    float4 a = *reinterpret_cast<const float4*>(p);
    float4 c = *reinterpret_cast<const float4*>(p + 4);
    ushort4 o0 = {f2bf(a.x), f2bf(a.y), f2bf(a.z), f2bf(a.w)};
    ushort4 o1 = {f2bf(c.x), f2bf(c.y), f2bf(c.z), f2bf(c.w)};
    unsigned short* q = whb + (size_t)i * 8;
    *reinterpret_cast<ushort4*>(q) = o0;
    *reinterpret_cast<ushort4*>(q + 4) = o1;
  }
}

// ---------------- CSR build ----------------
__global__ void count_kernel(const int* __restrict__ dst, int* __restrict__ deg,
                             int* __restrict__ rank, int e) {
  int i = blockIdx.x * blockDim.x + threadIdx.x;
  if (i < e) rank[i] = atomicAdd(&deg[dst[i]], 1);
}

__global__ __launch_bounds__(256) void scan1_kernel(const int* __restrict__ deg,
                                                    int* __restrict__ bsum, int n) {
  int i = blockIdx.x * 256 + threadIdx.x;
  int v = (i < n) ? deg[i] : 0;
  __shared__ int ls[256];
  ls[threadIdx.x] = v;
  __syncthreads();
  for (int d = 128; d > 0; d >>= 1) {
    if (threadIdx.x < (unsigned)d) ls[threadIdx.x] += ls[threadIdx.x + d];
    __syncthreads();
  }
  if (threadIdx.x == 0) bsum[blockIdx.x] = ls[0];
}

__global__ __launch_bounds__(256) void scan23_kernel(const int* __restrict__ deg,
                                                     const int* __restrict__ bsum,
                                                     int* __restrict__ off, int n, int nb) {
  __shared__ int bls[256];
  __shared__ int ls[256];
  int t = threadIdx.x;
  int bv = (t < nb) ? bsum[t] : 0;
  bls[t] = bv;
  __syncthreads();
  for (int d = 1; d < 256; d <<= 1) {
    int u = (t >= d) ? bls[t - d] : 0;
    __syncthreads();
    bls[t] += u;
    __syncthreads();
  }
  int i = blockIdx.x * 256 + t;
  int v = (i < n) ? deg[i] : 0;
  ls[t] = v;
  __syncthreads();
  for (int d = 1; d < 256; d <<= 1) {
    int u = (t >= d) ? ls[t - d] : 0;
    __syncthreads();
    ls[t] += u;
    __syncthreads();
  }
  int base = blockIdx.x ? bls[blockIdx.x - 1] : 0;
  if (i < n) off[i] = base + ls[t] - v;
  if (blockIdx.x == 0 && t == 0) off[n] = bls[nb - 1];
}

__global__ void fill_kernel(const int* __restrict__ src, const int* __restrict__ dst,
                            const int* __restrict__ rank, const int* __restrict__ off,
                            int* __restrict__ csr, int e) {
  int i = blockIdx.x * blockDim.x + threadIdx.x;
  if (i < e) csr[off[dst[i]] + rank[i]] = src[i];
}

// ---------------- quantize bf16 rows -> int8 table; tensor scale from pmax array ----------------
// Each block first reduces pmax[0..nblk) (L2-hot), then quantizes its slice.
// Block 0 stores the scalar into smax_out for downstream aggregate kernels.
__global__ __launch_bounds__(256) void quant_kernel(const unsigned short* __restrict__ hbf,
                                                    const float* __restrict__ pmax, int nblk,
                                                    unsigned* __restrict__ tab,
                                                    float* __restrict__ smax_out, int n16) {
  __shared__ float red[256];
  int t = threadIdx.x;
  float m = 0.f;
  for (int k = t; k < nblk; k += 256) m = fmaxf(m, pmax[k]);
  red[t] = m;
  __syncthreads();
  for (int d = 128; d > 0; d >>= 1) {
    if (t < d) red[t] = fmaxf(red[t], red[t + d]);
    __syncthreads();
  }
  float mx = red[0];
  if (blockIdx.x == 0 && t == 0) *smax_out = mx;
  int i = blockIdx.x * 256 + t;
  if (i >= n16) return;
  float qi = 127.0f / fmaxf(mx, 1e-30f);
  const unsigned short* p = hbf + (size_t)i * 8;
  ushort4 v0 = *reinterpret_cast<const ushort4*>(p);
  ushort4 v1 = *reinterpret_cast<const ushort4*>(p + 4);
  int q0 = (int)rintf(bf2f(v0.x) * qi), q1 = (int)rintf(bf2f(v0.y) * qi);
  int q2 = (int)rintf(bf2f(v0.z) * qi), q3 = (int)rintf(bf2f(v0.w) * qi);
  int q4 = (int)rintf(bf2f(v1.x) * qi), q5 = (int)rintf(bf2f(v1.y) * qi);
  int q6 = (int)rintf(bf2f(v1.z) * qi), q7 = (int)rintf(bf2f(v1.w) * qi);
  uint2 u = {pk_i8x4(q0, q1, q2, q3), pk_i8x4(q4, q5, q6, q7)};
  *reinterpret_cast<uint2*>(tab + (size_t)i * 2) = u;
}

// ---------------- mean aggregation: int8 rows, uniform tensor scale, BN+ReLU on read ----------------
template <bool BNIN>
__global__ __launch_bounds__(256) void aggregate_kernel(const unsigned* __restrict__ tab,
                                                        const float* __restrict__ smax,
                                                        const int* __restrict__ off,
                                                        const int* __restrict__ csr,
                                                        unsigned short* __restrict__ agg,
                                                        const float* __restrict__ stats,
                                                        const float* __restrict__ g,
                                                        const float* __restrict__ be,
                                                        float invn, int n) {
  int hw = (int)((blockIdx.x * blockDim.x + threadIdx.x) >> 5);
  int lane = threadIdx.x & 31;
  if (hw >= n) return;

  float sdeq = (*smax) * (1.0f / 127.0f);

  float sc0 = sdeq, sc1 = sdeq, sc2 = sdeq, sc3 = sdeq;
  float sh0 = 0.f, sh1 = 0.f, sh2 = 0.f, sh3 = 0.f;
  if (BNIN) {
    int c0 = lane * 4;
    float4 s  = *reinterpret_cast<const float4*>(stats + c0);
    float4 s2 = *reinterpret_cast<const float4*>(stats + 128 + c0);
    float4 gv = *reinterpret_cast<const float4*>(g + c0);
    float4 bv = *reinterpret_cast<const float4*>(be + c0);
    float m0 = s.x * invn, m1 = s.y * invn, m2 = s.z * invn, m3 = s.w * invn;
    float b0 = gv.x * rsqrtf(fmaxf(s2.x * invn - m0 * m0, 0.f) + 1e-5f);
    float b1 = gv.y * rsqrtf(fmaxf(s2.y * invn - m1 * m1, 0.f) + 1e-5f);
    float b2 = gv.z * rsqrtf(fmaxf(s2.z * invn - m2 * m2, 0.f) + 1e-5f);
    float b3 = gv.w * rsqrtf(fmaxf(s2.w * invn - m3 * m3, 0.f) + 1e-5f);
    sh0 = bv.x - m0 * b0; sh1 = bv.y - m1 * b1;
    sh2 = bv.z - m2 * b2; sh3 = bv.w - m3 * b3;
    sc0 = b0 * sdeq; sc1 = b1 * sdeq; sc2 = b2 * sdeq; sc3 = b3 * sdeq;
  }

  int s0 = off[hw], s1 = off[hw + 1];
  float a0 = 0.f, a1 = 0.f, a2 = 0.f, a3 = 0.f;

#define ACCV(u)                                                   \
  {                                                               \
    float q0 = (float)(((int)(u) << 24) >> 24);                   \
    float q1 = (float)(((int)(u) << 16) >> 24);                   \
    float q2 = (float)(((int)(u) << 8) >> 24);                    \
    float q3 = (float)((int)(u) >> 24);                           \
    if (BNIN) {                                                   \
      a0 += fmaxf(fmaf(q0, sc0, sh0), 0.f);                       \
      a1 += fmaxf(fmaf(q1, sc1, sh1), 0.f);                       \
      a2 += fmaxf(fmaf(q2, sc2, sh2), 0.f);                       \
      a3 += fmaxf(fmaf(q3, sc3, sh3), 0.f);                       \
    } else {                                                      \
      a0 += q0; a1 += q1; a2 += q2; a3 += q3;                     \
    }                                                             \
  }

  int j = s0;
  for (; j + 8 <= s1; j += 8) {
    int i0 = csr[j],     i1 = csr[j + 1], i2 = csr[j + 2], i3 = csr[j + 3];
    int i4 = csr[j + 4], i5 = csr[j + 5], i6 = csr[j + 6], i7 = csr[j + 7];
    unsigned u0 = tab[(size_t)i0 * 32 + lane];
    unsigned u1 = tab[(size_t)i1 * 32 + lane];
    unsigned u2 = tab[(size_t)i2 * 32 + lane];
    unsigned u3 = tab[(size_t)i3 * 32 + lane];
    unsigned u4 = tab[(size_t)i4 * 32 + lane];
    unsigned u5 = tab[(size_t)i5 * 32 + lane];
    unsigned u6 = tab[(size_t)i6 * 32 + lane];
    unsigned u7 = tab[(size_t)i7 * 32 + lane];
    ACCV(u0) ACCV(u1) ACCV(u2) ACCV(u3) ACCV(u4) ACCV(u5) ACCV(u6) ACCV(u7)
  }
  for (; j < s1; j++) {
    unsigned u0 = tab[(size_t)csr[j] * 32 + lane];
    ACCV(u0)
  }
#undef ACCV

  int d = s1 - s0;
  float inv = 1.0f / (float)(d > 0 ? d : 1);
  if (!BNIN) inv *= sdeq;
  ushort4 o = {f2bf(a0 * inv), f2bf(a1 * inv), f2bf(a2 * inv), f2bf(a3 * inv)};
  *reinterpret_cast<ushort4*>(agg + (size_t)hw * FC + lane * 4) = o;
}

// ---------------- MFMA GEMM: W in LDS (XOR-swizzled), A preloaded ----------------
// SMAX: per-block max of |pre-BN output| -> pmaxOut[blockIdx] (no atomics).
template <int NCOLS, int KTOT, bool DUAL, bool OUT_BF, bool STATS, bool BNIN, bool SMAX>
__global__ __launch_bounds__(256) void gemm_kernel(const unsigned short* __restrict__ A1,
                                                   const unsigned short* __restrict__ A2,
                                                   const unsigned short* __restrict__ W,
                                                   const float* __restrict__ bias,
                                                   void* __restrict__ Cout,
                                                   float* __restrict__ pmaxOut,
                                                   float* __restrict__ statsOut,
                                                   const float* __restrict__ statsIn,
                                                   const float* __restrict__ g,
                                                   const float* __restrict__ be,
                                                   float invn, int nrows) {
  constexpr int NKT = KTOT / 32;
  constexpr int NCF = NCOLS / 16;
  constexpr int RB = KTOT * 2;
  constexpr int WBYTES = NCOLS * KTOT * 2;
  __shared__ __align__(16) unsigned char Wl[WBYTES];
  __shared__ float scv[128], shv[128];

  int t = threadIdx.x;

  {
    constexpr int CH = WBYTES / 16 / 256;
#pragma unroll
    for (int c = 0; c < CH; c++) {
      int byte = (c * 256 + t) * 16;
      int row = byte / RB;
      int cb = byte % RB;
      float4 v = *reinterpret_cast<const float4*>(reinterpret_cast<const char*>(W) + byte);
      *reinterpret_cast<float4*>(Wl + row * RB + (cb ^ ((row & 7) << 4))) = v;
    }
  }

  if (BNIN && t < 128) {
    float mean = statsIn[t] * invn;
    float var = fmaxf(statsIn[128 + t] * invn - mean * mean, 0.f);
    float s = g[t] * rsqrtf(var + 1e-5f);
    scv[t] = s;
    shv[t] = be[t] - mean * s;
  }

  int w = t >> 6;
  int l = t & 63;
  int lm = l & 15;
  int hi = l >> 4;
  int lk = hi * 8;
  int row = blockIdx.x * 64 + w * 16 + lm;
  int rclamp = min(row, nrows - 1);

  bf16x8 a[NKT];
#pragma unroll
  for (int kt = 0; kt < NKT; kt++) {
    const unsigned short* Ap;
    int kk;
    if (!DUAL || kt < NKT / 2) { Ap = A1; kk = kt * 32; }
    else                       { Ap = A2; kk = (kt - NKT / 2) * 32; }
    a[kt] = *reinterpret_cast<const bf16x8*>(Ap + (size_t)rclamp * 128 + kk + lk);
  }

  f32x4 acc[NCF];
#pragma unroll
  for (int cf = 0; cf < NCF; cf++) acc[cf] = {0.f, 0.f, 0.f, 0.f};

  __syncthreads();

  if (BNIN) {
#pragma unroll
    for (int kt = 0; kt < NKT; kt++) {
      if (!DUAL || kt >= NKT / 2) {
        int ch0 = (DUAL ? (kt - NKT / 2) : kt) * 32 + lk;
#pragma unroll
        for (int j = 0; j < 8; j++) {
          float v = (float)a[kt][j];
          v = fmaxf(fmaf(v, scv[ch0 + j], shv[ch0 + j]), 0.f);
          a[kt][j] = (__bf16)v;
        }
      }
    }
  }

#pragma unroll
  for (int kt = 0; kt < NKT; kt++) {
#pragma unroll
    for (int cf = 0; cf < NCF; cf++) {
      int r = cf * 16 + lm;
      int cb = kt * 64 + hi * 16;
      bf16x8 b = *reinterpret_cast<const bf16x8*>(Wl + r * RB + (cb ^ ((r & 7) << 4)));
      acc[cf] = __builtin_amdgcn_mfma_f32_16x16x32_bf16(a[kt], b, acc[cf], 0, 0, 0);
    }
  }

  // fold bias
#pragma unroll
  for (int cf = 0; cf < NCF; cf++) {
    float bs = bias[cf * 16 + lm];
#pragma unroll
    for (int r = 0; r < 4; r++) acc[cf][r] += bs;
  }

  if (SMAX) {
    float m = 0.f;
#pragma unroll
    for (int cf = 0; cf < NCF; cf++)
#pragma unroll
      for (int r = 0; r < 4; r++) m = fmaxf(m, fabsf(acc[cf][r]));
    m = fmaxf(m, __shfl_xor(m, 1));
    m = fmaxf(m, __shfl_xor(m, 2));
    m = fmaxf(m, __shfl_xor(m, 4));
    m = fmaxf(m, __shfl_xor(m, 8));
    m = fmaxf(m, __shfl_xor(m, 16));
    m = fmaxf(m, __shfl_xor(m, 32));
    __shared__ float rmax[4];
    if (l == 0) rmax[w] = m;
    __syncthreads();
    if (t == 0)
      pmaxOut[blockIdx.x] = fmaxf(fmaxf(rmax[0], rmax[1]), fmaxf(rmax[2], rmax[3]));
  }

  __shared__ float wsum[4][NCOLS];
  __shared__ float wsq[4][NCOLS];

  int orow0 = blockIdx.x * 64 + w * 16 + hi * 4;
#pragma unroll
  for (int cf = 0; cf < NCF; cf++) {
    int col = cf * 16 + lm;
    float s = 0.f, s2 = 0.f;
#pragma unroll
    for (int r = 0; r < 4; r++) {
      int orow = orow0 + r;
      bool ok = orow < nrows;
      float v = acc[cf][r];
      if (ok) {
        if (OUT_BF)
          ((unsigned short*)Cout)[(size_t)orow * NCOLS + col] = f2bf(v);
        else
          ((float*)Cout)[(size_t)orow * NCOLS + col] = v;
      }
      if (STATS) {
        float vv = ok ? v : 0.f;
        s += vv; s2 += vv * vv;
      }
    }
    if (STATS) {
      s  += __shfl_xor(s, 16);  s  += __shfl_xor(s, 32);
      s2 += __shfl_xor(s2, 16); s2 += __shfl_xor(s2, 32);
      if (l < 16) { wsum[w][col] = s; wsq[w][col] = s2; }
    }
  }
  if (STATS) {
    __syncthreads();
    if (t < NCOLS) {
      atomicAdd(&statsOut[t], wsum[0][t] + wsum[1][t] + wsum[2][t] + wsum[3][t]);
    } else if (t < 2 * NCOLS) {
      int c = t - NCOLS;
      atomicAdd(&statsOut[t], wsq[0][c] + wsq[1][c] + wsq[2][c] + wsq[3][c]);
    }
  }
}

// ---------------- launch ----------------
extern "C" void kernel_launch(void* const* d_in, const int* in_sizes, int n_in,
                              void* d_out, int out_size, void* d_ws, size_t ws_size,
                              hipStream_t stream) {
  const float* x   = (const float*)d_in[0];
  const int*   ei  = (const int*)d_in[1];
  const float* w1l = (const float*)d_in[2];
  const float* w1r = (const float*)d_in[3];
  const float* b1c = (const float*)d_in[4];
  const float* w2l = (const float*)d_in[5];
  const float* w2r = (const float*)d_in[6];
  const float* b2c = (const float*)d_in[7];
  const float* w3l = (const float*)d_in[8];
  const float* w3r = (const float*)d_in[9];
  const float* b3c = (const float*)d_in[10];
  const float* g1  = (const float*)d_in[11];
  const float* be1 = (const float*)d_in[12];
  const float* g2  = (const float*)d_in[13];
  const float* be2 = (const float*)d_in[14];
  const float* g3  = (const float*)d_in[15];
  const float* be3 = (const float*)d_in[16];
  const float* wh  = (const float*)d_in[17];
  const float* bh  = (const float*)d_in[18];

  int n = in_sizes[0] / FC;
  int e = in_sizes[1] / 2;
  const int* srcI = ei;
  const int* dstI = ei + e;

  char* p = (char*)d_ws;
  auto take = [&](size_t bytes) {
    char* q = p;
    p += (bytes + 255) & ~(size_t)255;
    return q;
  };
  int nb = (n + 255) / 256;
  int nx8 = n * 16;
  int xb = (nx8 + 255) / 256;
  int cb = (e + 255) / 256;
  int gb = (n + 63) / 64;
  int ab = (n + 7) / 8;

  int* deg  = (int*)take((size_t)n * 4);
  int* off  = (int*)take((size_t)(n + 1) * 4);
  int* bsum = (int*)take((size_t)nb * 4);
  int* rank = (int*)take((size_t)e * 4);
  int* csr  = (int*)take((size_t)e * 4);
  unsigned short* x_bf = (unsigned short*)take((size_t)n * FC * 2);
  unsigned short* agg  = (unsigned short*)take((size_t)n * FC * 2);
  unsigned short* h1   = (unsigned short*)take((size_t)n * FC * 2);
  unsigned short* h2   = (unsigned short*)take((size_t)n * FC * 2);
  unsigned char*  ai8  = (unsigned char*)take((size_t)n * FC);   // int8 gather table (reused)
  float*    pmax  = (float*)take((size_t)xb * 4);                 // per-block max scratch
  unsigned short* wc1  = (unsigned short*)take(128 * 256 * 2);
  unsigned short* wc2  = (unsigned short*)take(128 * 256 * 2);
  unsigned short* wc3  = (unsigned short*)take(128 * 256 * 2);
  unsigned short* whb  = (unsigned short*)take(64 * 128 * 2);
  float*    stats = (float*)take(3 * 256 * 4);
  float*    smax  = (float*)take(4 * 4);   // [0]=x, [1]=h1, [2]=h2

  float invn = 1.0f / (float)n;

  zero_kernel<<<nb, 256, 0, stream>>>(deg, stats, smax, n);
  convert_kernel<<<xb + 52, 256, 0, stream>>>(x, w1l, w1r, w2l, w2r, w3l, w3r, wh,
                                              x_bf, pmax, wc1, wc2, wc3, whb, nx8, xb);
  count_kernel<<<cb, 256, 0, stream>>>(dstI, deg, rank, e);
  scan1_kernel<<<nb, 256, 0, stream>>>(deg, bsum, n);
  scan23_kernel<<<nb, 256, 0, stream>>>(deg, bsum, off, n, nb);
  fill_kernel<<<cb, 256, 0, stream>>>(srcI, dstI, rank, off, csr, e);
  quant_kernel<<<xb, 256, 0, stream>>>(x_bf, pmax, xb, (unsigned*)ai8, smax, nx8);

  // layer 1: gather int8(x); root = bf16 x; per-block max of h1 -> pmax
  aggregate_kernel<false><<<ab, 256, 0, stream>>>((const unsigned*)ai8, smax, off, csr, agg,
                                                  nullptr, nullptr, nullptr, invn, n);
  gemm_kernel<128, 256, true, true, true, false, true><<<gb, 256, 0, stream>>>(
      agg, x_bf, wc1, b1c, h1, pmax, stats, nullptr, nullptr, nullptr, invn, n);
  quant_kernel<<<xb, 256, 0, stream>>>(h1, pmax, gb, (unsigned*)ai8, smax + 1, nx8);

  // layer 2: gather int8(h1) with BN1 on read; root = bf16 h1 (BN1 in gemm)
  aggregate_kernel<true><<<ab, 256, 0, stream>>>((const unsigned*)ai8, smax + 1, off, csr, agg,
                                                 stats, g1, be1, invn, n);
  gemm_kernel<128, 256, true, true, true, true, true><<<gb, 256, 0, stream>>>(
      agg, h1, wc2, b2c, h2, pmax, stats + 256, stats, g1, be1, invn, n);
  quant_kernel<<<xb, 256, 0, stream>>>(h2, pmax, gb, (unsigned*)ai8, smax + 2, nx8);

  // layer 3: gather int8(h2) with BN2 on read
  aggregate_kernel<true><<<ab, 256, 0, stream>>>((const unsigned*)ai8, smax + 2, off, csr, agg,
                                                 stats + 256, g2, be2, invn, n);
  gemm_kernel<128, 256, true, true, true, true, false><<<gb, 256, 0, stream>>>(
      agg, h2, wc3, b3c, h1, nullptr, stats + 512, stats + 256, g2, be2, invn, n);

  // head: BN3 on read of h1
  gemm_kernel<64, 128, false, false, false, true, false><<<gb, 256, 0, stream>>>(
      h1, nullptr, whb, bh, d_out, nullptr, nullptr, stats + 512, g3, be3, invn, n);
}

// Round 16
// 276.111 us; speedup vs baseline: 1.5386x; 1.0011x over previous
//
#include <hip/hip_runtime.h>

static constexpr int FC = 128;

typedef __attribute__((ext_vector_type(8))) __bf16 bf16x8;
typedef __attribute__((ext_vector_type(4))) float f32x4;

__device__ __forceinline__ unsigned short f2bf(float f) {
  unsigned u = __float_as_uint(f);
  unsigned r = (u + 0x7FFF + ((u >> 16) & 1)) >> 16;
  return (unsigned short)r;
}
__device__ __forceinline__ float bf2f(unsigned short h) {
  return __uint_as_float((unsigned)h << 16);
}
__device__ __forceinline__ unsigned pk_i8x4(int q0, int q1, int q2, int q3) {
  return (unsigned)(q0 & 0xff) | ((unsigned)(q1 & 0xff) << 8) |
         ((unsigned)(q2 & 0xff) << 16) | ((unsigned)(q3 & 0xff) << 24);
}

// ---------------- zero deg + stats ----------------
__global__ __launch_bounds__(256) void zero_kernel(int* __restrict__ deg,
                                                   float* __restrict__ stats, int n) {
  int i = blockIdx.x * 256 + threadIdx.x;
  if (i < n) deg[i] = 0;
  if (i < 768) stats[i] = 0.f;
}

// ---------------- fused: edge count+rank | x->bf16+int8(row scale) | W packs ----------------
// blocks [0,cb): count. [cb,cb+nxq): x rows (8 rows/block, half-wave each).
// [..+48): layer W. [..+4): head W.  deg must be pre-zeroed (zero_kernel).
__global__ __launch_bounds__(256) void convert_kernel(
    const int* __restrict__ dst, int* __restrict__ deg, int* __restrict__ rank, int e, int cb,
    const float* __restrict__ x, const float* __restrict__ w1l, const float* __restrict__ w1r,
    const float* __restrict__ w2l, const float* __restrict__ w2r,
    const float* __restrict__ w3l, const float* __restrict__ w3r,
    const float* __restrict__ wh,
    unsigned short* __restrict__ x_bf, unsigned* __restrict__ xi8,
    float* __restrict__ xsc,
    unsigned short* __restrict__ wc1,
    unsigned short* __restrict__ wc2, unsigned short* __restrict__ wc3,
    unsigned short* __restrict__ whb, int n, int nxq) {
  int b = blockIdx.x;
  int t = threadIdx.x;
  if (b < cb) {
    int i = b * 256 + t;
    if (i < e) rank[i] = atomicAdd(&deg[dst[i]], 1);
    return;
  }
  int r0 = b - cb;
  if (r0 < nxq) {
    int row = r0 * 8 + (t >> 5);
    int lane = t & 31;
    if (row >= n) return;
    float4 a = *reinterpret_cast<const float4*>(x + (size_t)row * FC + lane * 4);
    ushort4 o = {f2bf(a.x), f2bf(a.y), f2bf(a.z), f2bf(a.w)};
    *reinterpret_cast<ushort4*>(x_bf + (size_t)row * FC + lane * 4) = o;
    float m = fmaxf(fmaxf(fabsf(a.x), fabsf(a.y)), fmaxf(fabsf(a.z), fabsf(a.w)));
    m = fmaxf(m, __shfl_xor(m, 1));
    m = fmaxf(m, __shfl_xor(m, 2));
    m = fmaxf(m, __shfl_xor(m, 4));
    m = fmaxf(m, __shfl_xor(m, 8));
    m = fmaxf(m, __shfl_xor(m, 16));
    float inv = 127.0f / fmaxf(m, 1e-30f);
    int q0 = (int)rintf(a.x * inv), q1 = (int)rintf(a.y * inv);
    int q2 = (int)rintf(a.z * inv), q3 = (int)rintf(a.w * inv);
    xi8[(size_t)row * 32 + lane] = pk_i8x4(q0, q1, q2, q3);
    if (lane == 0) xsc[row] = m * (1.0f / 127.0f);
    return;
  }
  int r = r0 - nxq;
  if (r < 48) {
    int layer = r >> 4;
    const float* wl = layer == 0 ? w1l : (layer == 1 ? w2l : w3l);
    const float* wr = layer == 0 ? w1r : (layer == 1 ? w2r : w3r);
    unsigned short* out = layer == 0 ? wc1 : (layer == 1 ? wc2 : wc3);
    int i = (r & 15) * 256 + t;   // 0..4095
    int row = i >> 5;
    int k8 = (i & 31) * 8;
    const float* src = (k8 < 128) ? (wl + (size_t)row * 128 + k8)
                                  : (wr + (size_t)row * 128 + (k8 - 128));
    float4 a = *reinterpret_cast<const float4*>(src);
    float4 c = *reinterpret_cast<const float4*>(src + 4);
    ushort4 o0 = {f2bf(a.x), f2bf(a.y), f2bf(a.z), f2bf(a.w)};
    ushort4 o1 = {f2bf(c.x), f2bf(c.y), f2bf(c.z), f2bf(c.w)};
    unsigned short* q = out + (size_t)row * 256 + k8;
    *reinterpret_cast<ushort4*>(q) = o0;
    *reinterpret_cast<ushort4*>(q + 4) = o1;
  } else {
    int i = (r - 48) * 256 + t;   // 0..1023
    const float* p = wh + (size_t)i * 8;
    float4 a = *reinterpret_cast<const float4*>(p);
    float4 c = *reinterpret_cast<const float4*>(p + 4);
    ushort4 o0 = {f2bf(a.x), f2bf(a.y), f2bf(a.z), f2bf(a.w)};
    ushort4 o1 = {f2bf(c.x), f2bf(c.y), f2bf(c.z), f2bf(c.w)};
    unsigned short* q = whb + (size_t)i * 8;
    *reinterpret_cast<ushort4*>(q) = o0;
    *reinterpret_cast<ushort4*>(q + 4) = o1;
  }
}

// ---------------- CSR scans + fill ----------------
__global__ __launch_bounds__(256) void scan1_kernel(const int* __restrict__ deg,
                                                    int* __restrict__ bsum, int n) {
  int i = blockIdx.x * 256 + threadIdx.x;
  int v = (i < n) ? deg[i] : 0;
  __shared__ int ls[256];
  ls[threadIdx.x] = v;
  __syncthreads();
  for (int d = 128; d > 0; d >>= 1) {
    if (threadIdx.x < (unsigned)d) ls[threadIdx.x] += ls[threadIdx.x + d];
    __syncthreads();
  }
  if (threadIdx.x == 0) bsum[blockIdx.x] = ls[0];
}

__global__ __launch_bounds__(256) void scan23_kernel(const int* __restrict__ deg,
                                                     const int* __restrict__ bsum,
                                                     int* __restrict__ off, int n, int nb) {
  __shared__ int bls[256];
  __shared__ int ls[256];
  int t = threadIdx.x;
  int bv = (t < nb) ? bsum[t] : 0;
  bls[t] = bv;
  __syncthreads();
  for (int d = 1; d < 256; d <<= 1) {
    int u = (t >= d) ? bls[t - d] : 0;
    __syncthreads();
    bls[t] += u;
    __syncthreads();
  }
  int i = blockIdx.x * 256 + t;
  int v = (i < n) ? deg[i] : 0;
  ls[t] = v;
  __syncthreads();
  for (int d = 1; d < 256; d <<= 1) {
    int u = (t >= d) ? ls[t - d] : 0;
    __syncthreads();
    ls[t] += u;
    __syncthreads();
  }
  int base = blockIdx.x ? bls[blockIdx.x - 1] : 0;
  if (i < n) off[i] = base + ls[t] - v;
  if (blockIdx.x == 0 && t == 0) off[n] = bls[nb - 1];
}

__global__ void fill_kernel(const int* __restrict__ src, const int* __restrict__ dst,
                            const int* __restrict__ rank, const int* __restrict__ off,
                            int* __restrict__ csr, int e) {
  int i = blockIdx.x * blockDim.x + threadIdx.x;
  if (i < e) csr[off[dst[i]] + rank[i]] = src[i];
}

// ---------------- mean aggregation: int8 rows + per-row scale, BN+ReLU on read ----------------
// xi8: [n][32] uints. xsc: [n] row scales. agg out: bf16 [n][128].
template <bool BNIN>
__global__ __launch_bounds__(256) void aggregate_kernel(const unsigned* __restrict__ xi8,
                                                        const float* __restrict__ xsc,
                                                        const int* __restrict__ off,
                                                        const int* __restrict__ csr,
                                                        unsigned short* __restrict__ agg,
                                                        const float* __restrict__ stats,
                                                        const float* __restrict__ g,
                                                        const float* __restrict__ be,
                                                        float invn, int n) {
  int hw = (int)((blockIdx.x * blockDim.x + threadIdx.x) >> 5);
  int lane = threadIdx.x & 31;
  if (hw >= n) return;

  float sc0 = 1.f, sc1 = 1.f, sc2 = 1.f, sc3 = 1.f;
  float sh0 = 0.f, sh1 = 0.f, sh2 = 0.f, sh3 = 0.f;
  if (BNIN) {
    int c0 = lane * 4;
    float4 s  = *reinterpret_cast<const float4*>(stats + c0);
    float4 s2 = *reinterpret_cast<const float4*>(stats + 128 + c0);
    float4 gv = *reinterpret_cast<const float4*>(g + c0);
    float4 bv = *reinterpret_cast<const float4*>(be + c0);
    float m0 = s.x * invn, m1 = s.y * invn, m2 = s.z * invn, m3 = s.w * invn;
    sc0 = gv.x * rsqrtf(fmaxf(s2.x * invn - m0 * m0, 0.f) + 1e-5f);
    sc1 = gv.y * rsqrtf(fmaxf(s2.y * invn - m1 * m1, 0.f) + 1e-5f);
    sc2 = gv.z * rsqrtf(fmaxf(s2.z * invn - m2 * m2, 0.f) + 1e-5f);
    sc3 = gv.w * rsqrtf(fmaxf(s2.w * invn - m3 * m3, 0.f) + 1e-5f);
    sh0 = bv.x - m0 * sc0; sh1 = bv.y - m1 * sc1;
    sh2 = bv.z - m2 * sc2; sh3 = bv.w - m3 * sc3;
  }

  int s0 = off[hw], s1 = off[hw + 1];
  float a0 = 0.f, a1 = 0.f, a2 = 0.f, a3 = 0.f;

#define ACCV(u, sv)                                               \
  {                                                               \
    float q0 = (float)(((int)(u) << 24) >> 24);                   \
    float q1 = (float)(((int)(u) << 16) >> 24);                   \
    float q2 = (float)(((int)(u) << 8) >> 24);                    \
    float q3 = (float)((int)(u) >> 24);                           \
    if (BNIN) {                                                   \
      a0 += fmaxf(fmaf(q0, (sv) * sc0, sh0), 0.f);                \
      a1 += fmaxf(fmaf(q1, (sv) * sc1, sh1), 0.f);                \
      a2 += fmaxf(fmaf(q2, (sv) * sc2, sh2), 0.f);                \
      a3 += fmaxf(fmaf(q3, (sv) * sc3, sh3), 0.f);                \
    } else {                                                      \
      a0 = fmaf(q0, (sv), a0);                                    \
      a1 = fmaf(q1, (sv), a1);                                    \
      a2 = fmaf(q2, (sv), a2);                                    \
      a3 = fmaf(q3, (sv), a3);                                    \
    }                                                             \
  }

  int j = s0;
  for (; j + 8 <= s1; j += 8) {
    int i0 = __builtin_nontemporal_load(csr + j);
    int i1 = __builtin_nontemporal_load(csr + j + 1);
    int i2 = __builtin_nontemporal_load(csr + j + 2);
    int i3 = __builtin_nontemporal_load(csr + j + 3);
    int i4 = __builtin_nontemporal_load(csr + j + 4);
    int i5 = __builtin_nontemporal_load(csr + j + 5);
    int i6 = __builtin_nontemporal_load(csr + j + 6);
    int i7 = __builtin_nontemporal_load(csr + j + 7);
    unsigned u0 = xi8[(size_t)i0 * 32 + lane];
    unsigned u1 = xi8[(size_t)i1 * 32 + lane];
    unsigned u2 = xi8[(size_t)i2 * 32 + lane];
    unsigned u3 = xi8[(size_t)i3 * 32 + lane];
    unsigned u4 = xi8[(size_t)i4 * 32 + lane];
    unsigned u5 = xi8[(size_t)i5 * 32 + lane];
    unsigned u6 = xi8[(size_t)i6 * 32 + lane];
    unsigned u7 = xi8[(size_t)i7 * 32 + lane];
    float sv0 = xsc[i0], sv1 = xsc[i1], sv2 = xsc[i2], sv3 = xsc[i3];
    float sv4 = xsc[i4], sv5 = xsc[i5], sv6 = xsc[i6], sv7 = xsc[i7];
    ACCV(u0, sv0) ACCV(u1, sv1) ACCV(u2, sv2) ACCV(u3, sv3)
    ACCV(u4, sv4) ACCV(u5, sv5) ACCV(u6, sv6) ACCV(u7, sv7)
  }
  for (; j < s1; j++) {
    int i0 = __builtin_nontemporal_load(csr + j);
    unsigned u0 = xi8[(size_t)i0 * 32 + lane];
    float sv0 = xsc[i0];
    ACCV(u0, sv0)
  }
#undef ACCV

  int d = s1 - s0;
  float inv = 1.0f / (float)(d > 0 ? d : 1);
  ushort4 o = {f2bf(a0 * inv), f2bf(a1 * inv), f2bf(a2 * inv), f2bf(a3 * inv)};
  *reinterpret_cast<ushort4*>(agg + (size_t)hw * FC + lane * 4) = o;
}

// ---------------- MFMA GEMM: W in LDS (XOR-swizzled), A preloaded ----------------
// OUT_I8: store int8(v) (pre-BN) + per-row scale for next layer's gather.
template <int NCOLS, int KTOT, bool DUAL, bool OUT_BF, bool STATS, bool BNIN, bool OUT_I8>
__global__ __launch_bounds__(256) void gemm_kernel(const unsigned short* __restrict__ A1,
                                                   const unsigned short* __restrict__ A2,
                                                   const unsigned short* __restrict__ W,
                                                   const float* __restrict__ bias,
                                                   void* __restrict__ Cout,
                                                   unsigned char* __restrict__ h8,
                                                   float* __restrict__ hsc,
                                                   float* __restrict__ statsOut,
                                                   const float* __restrict__ statsIn,
                                                   const float* __restrict__ g,
                                                   const float* __restrict__ be,
                                                   float invn, int nrows) {
  constexpr int NKT = KTOT / 32;
  constexpr int NCF = NCOLS / 16;
  constexpr int RB = KTOT * 2;
  constexpr int WBYTES = NCOLS * KTOT * 2;
  __shared__ __align__(16) unsigned char Wl[WBYTES];
  __shared__ float scv[128], shv[128];

  int t = threadIdx.x;

  {
    constexpr int CH = WBYTES / 16 / 256;
#pragma unroll
    for (int c = 0; c < CH; c++) {
      int byte = (c * 256 + t) * 16;
      int row = byte / RB;
      int cb = byte % RB;
      float4 v = *reinterpret_cast<const float4*>(reinterpret_cast<const char*>(W) + byte);
      *reinterpret_cast<float4*>(Wl + row * RB + (cb ^ ((row & 7) << 4))) = v;
    }
  }

  if (BNIN && t < 128) {
    float mean = statsIn[t] * invn;
    float var = fmaxf(statsIn[128 + t] * invn - mean * mean, 0.f);
    float s = g[t] * rsqrtf(var + 1e-5f);
    scv[t] = s;
    shv[t] = be[t] - mean * s;
  }

  int w = t >> 6;
  int l = t & 63;
  int lm = l & 15;
  int hi = l >> 4;
  int lk = hi * 8;
  int row = blockIdx.x * 64 + w * 16 + lm;
  int rclamp = min(row, nrows - 1);

  bf16x8 a[NKT];
#pragma unroll
  for (int kt = 0; kt < NKT; kt++) {
    const unsigned short* Ap;
    int kk;
    if (!DUAL || kt < NKT / 2) { Ap = A1; kk = kt * 32; }
    else                       { Ap = A2; kk = (kt - NKT / 2) * 32; }
    a[kt] = *reinterpret_cast<const bf16x8*>(Ap + (size_t)rclamp * 128 + kk + lk);
  }

  f32x4 acc[NCF];
#pragma unroll
  for (int cf = 0; cf < NCF; cf++) acc[cf] = {0.f, 0.f, 0.f, 0.f};

  __syncthreads();

  if (BNIN) {
#pragma unroll
    for (int kt = 0; kt < NKT; kt++) {
      if (!DUAL || kt >= NKT / 2) {
        int ch0 = (DUAL ? (kt - NKT / 2) : kt) * 32 + lk;
#pragma unroll
        for (int j = 0; j < 8; j++) {
          float v = (float)a[kt][j];
          v = fmaxf(fmaf(v, scv[ch0 + j], shv[ch0 + j]), 0.f);
          a[kt][j] = (__bf16)v;
        }
      }
    }
  }

#pragma unroll
  for (int kt = 0; kt < NKT; kt++) {
#pragma unroll
    for (int cf = 0; cf < NCF; cf++) {
      int r = cf * 16 + lm;
      int cb = kt * 64 + hi * 16;
      bf16x8 b = *reinterpret_cast<const bf16x8*>(Wl + r * RB + (cb ^ ((r & 7) << 4)));
      acc[cf] = __builtin_amdgcn_mfma_f32_16x16x32_bf16(a[kt], b, acc[cf], 0, 0, 0);
    }
  }

  // fold bias in-place
#pragma unroll
  for (int cf = 0; cf < NCF; cf++) {
    float bs = bias[cf * 16 + lm];
#pragma unroll
    for (int r = 0; r < 4; r++) acc[cf][r] += bs;
  }

  // per-output-row scale for int8
  float qinv[4], qs[4];
  if (OUT_I8) {
#pragma unroll
    for (int r = 0; r < 4; r++) {
      float m = 0.f;
#pragma unroll
      for (int cf = 0; cf < NCF; cf++) m = fmaxf(m, fabsf(acc[cf][r]));
      m = fmaxf(m, __shfl_xor(m, 1));
      m = fmaxf(m, __shfl_xor(m, 2));
      m = fmaxf(m, __shfl_xor(m, 4));
      m = fmaxf(m, __shfl_xor(m, 8));
      qinv[r] = 127.0f / fmaxf(m, 1e-30f);
      qs[r] = m * (1.0f / 127.0f);
    }
  }

  __shared__ float wsum[4][NCOLS];
  __shared__ float wsq[4][NCOLS];

  int orow0 = blockIdx.x * 64 + w * 16 + hi * 4;
#pragma unroll
  for (int cf = 0; cf < NCF; cf++) {
    int col = cf * 16 + lm;
    float s = 0.f, s2 = 0.f;
#pragma unroll
    for (int r = 0; r < 4; r++) {
      int orow = orow0 + r;
      bool ok = orow < nrows;
      float v = acc[cf][r];
      if (ok) {
        if (OUT_BF)
          ((unsigned short*)Cout)[(size_t)orow * NCOLS + col] = f2bf(v);
        else
          ((float*)Cout)[(size_t)orow * NCOLS + col] = v;
        if (OUT_I8)
          h8[(size_t)orow * NCOLS + col] = (unsigned char)((int)rintf(v * qinv[r]) & 0xff);
      }
      if (STATS) {
        float vv = ok ? v : 0.f;
        s += vv; s2 += vv * vv;
      }
    }
    if (STATS) {
      s  += __shfl_xor(s, 16);  s  += __shfl_xor(s, 32);
      s2 += __shfl_xor(s2, 16); s2 += __shfl_xor(s2, 32);
      if (l < 16) { wsum[w][col] = s; wsq[w][col] = s2; }
    }
  }
  if (OUT_I8 && lm == 0) {
#pragma unroll
    for (int r = 0; r < 4; r++) {
      int orow = orow0 + r;
      if (orow < nrows) hsc[orow] = qs[r];
    }
  }
  if (STATS) {
    __syncthreads();
    if (t < NCOLS) {
      atomicAdd(&statsOut[t], wsum[0][t] + wsum[1][t] + wsum[2][t] + wsum[3][t]);
    } else if (t < 2 * NCOLS) {
      int c = t - NCOLS;
      atomicAdd(&statsOut[t], wsq[0][c] + wsq[1][c] + wsq[2][c] + wsq[3][c]);
    }
  }
}

// ---------------- launch ----------------
extern "C" void kernel_launch(void* const* d_in, const int* in_sizes, int n_in,
                              void* d_out, int out_size, void* d_ws, size_t ws_size,
                              hipStream_t stream) {
  const float* x   = (const float*)d_in[0];
  const int*   ei  = (const int*)d_in[1];
  const float* w1l = (const float*)d_in[2];
  const float* w1r = (const float*)d_in[3];
  const float* b1c = (const float*)d_in[4];
  const float* w2l = (const float*)d_in[5];
  const float* w2r = (const float*)d_in[6];
  const float* b2c = (const float*)d_in[7];
  const float* w3l = (const float*)d_in[8];
  const float* w3r = (const float*)d_in[9];
  const float* b3c = (const float*)d_in[10];
  const float* g1  = (const float*)d_in[11];
  const float* be1 = (const float*)d_in[12];
  const float* g2  = (const float*)d_in[13];
  const float* be2 = (const float*)d_in[14];
  const float* g3  = (const float*)d_in[15];
  const float* be3 = (const float*)d_in[16];
  const float* wh  = (const float*)d_in[17];
  const float* bh  = (const float*)d_in[18];

  int n = in_sizes[0] / FC;
  int e = in_sizes[1] / 2;
  const int* srcI = ei;
  const int* dstI = ei + e;

  char* p = (char*)d_ws;
  auto take = [&](size_t bytes) {
    char* q = p;
    p += (bytes + 255) & ~(size_t)255;
    return q;
  };
  int nb = (n + 255) / 256;
  int cb = (e + 255) / 256;
  int nxq = (n + 7) / 8;
  int gb = (n + 63) / 64;
  int ab = (n + 7) / 8;

  int* deg  = (int*)take((size_t)n * 4);
  int* off  = (int*)take((size_t)(n + 1) * 4);
  int* bsum = (int*)take((size_t)nb * 4);
  int* rank = (int*)take((size_t)e * 4);
  int* csr  = (int*)take((size_t)e * 4);
  unsigned short* x_bf = (unsigned short*)take((size_t)n * FC * 2);
  unsigned short* agg  = (unsigned short*)take((size_t)n * FC * 2);
  unsigned short* h1   = (unsigned short*)take((size_t)n * FC * 2);
  unsigned short* h2   = (unsigned short*)take((size_t)n * FC * 2);
  unsigned char*  ai8  = (unsigned char*)take((size_t)n * FC);
  float*          asc  = (float*)take((size_t)n * 4);
  unsigned short* wc1  = (unsigned short*)take(128 * 256 * 2);
  unsigned short* wc2  = (unsigned short*)take(128 * 256 * 2);
  unsigned short* wc3  = (unsigned short*)take(128 * 256 * 2);
  unsigned short* whb  = (unsigned short*)take(64 * 128 * 2);
  float* stats = (float*)take(3 * 256 * 4);

  float invn = 1.0f / (float)n;

  zero_kernel<<<nb, 256, 0, stream>>>(deg, stats, n);
  convert_kernel<<<cb + nxq + 52, 256, 0, stream>>>(
      dstI, deg, rank, e, cb, x, w1l, w1r, w2l, w2r, w3l, w3r, wh,
      x_bf, (unsigned*)ai8, asc, wc1, wc2, wc3, whb, n, nxq);

  scan1_kernel<<<nb, 256, 0, stream>>>(deg, bsum, n);
  scan23_kernel<<<nb, 256, 0, stream>>>(deg, bsum, off, n, nb);
  fill_kernel<<<cb, 256, 0, stream>>>(srcI, dstI, rank, off, csr, e);

  // layer 1: gather int8(x); root = bf16 x; emit h1 bf16 + int8 into ai8/asc
  aggregate_kernel<false><<<ab, 256, 0, stream>>>((const unsigned*)ai8, asc, off, csr, agg,
                                                  nullptr, nullptr, nullptr, invn, n);
  gemm_kernel<128, 256, true, true, true, false, true><<<gb, 256, 0, stream>>>(
      agg, x_bf, wc1, b1c, h1, ai8, asc, stats, nullptr, nullptr, nullptr, invn, n);

  // layer 2: gather int8(h1) with BN1 on read; root = bf16 h1 (BN1 in gemm)
  aggregate_kernel<true><<<ab, 256, 0, stream>>>((const unsigned*)ai8, asc, off, csr, agg,
                                                 stats, g1, be1, invn, n);
  gemm_kernel<128, 256, true, true, true, true, true><<<gb, 256, 0, stream>>>(
      agg, h1, wc2, b2c, h2, ai8, asc, stats + 256, stats, g1, be1, invn, n);

  // layer 3: gather int8(h2) with BN2 on read; no int8 out (head reads bf16)
  aggregate_kernel<true><<<ab, 256, 0, stream>>>((const unsigned*)ai8, asc, off, csr, agg,
                                                 stats + 256, g2, be2, invn, n);
  gemm_kernel<128, 256, true, true, true, true, false><<<gb, 256, 0, stream>>>(
      agg, h2, wc3, b3c, h1, nullptr, nullptr, stats + 512, stats + 256, g2, be2, invn, n);

  // head: BN3 on read of h1
  gemm_kernel<64, 128, false, false, false, true, false><<<gb, 256, 0, stream>>>(
      h1, nullptr, whb, bh, d_out, nullptr, nullptr, nullptr, stats + 512, g3, be3, invn, n);
}

// Round 17
// 257.044 us; speedup vs baseline: 1.6527x; 1.0742x over previous
//
#include <hip/hip_runtime.h>

static constexpr int FC = 128;

typedef __attribute__((ext_vector_type(8))) __bf16 bf16x8;
typedef __attribute__((ext_vector_type(4))) float f32x4;

__device__ __forceinline__ unsigned short f2bf(float f) {
  unsigned u = __float_as_uint(f);
  unsigned r = (u + 0x7FFF + ((u >> 16) & 1)) >> 16;
  return (unsigned short)r;
}
__device__ __forceinline__ float bf2f(unsigned short h) {
  return __uint_as_float((unsigned)h << 16);
}
__device__ __forceinline__ unsigned pk_i8x4(int q0, int q1, int q2, int q3) {
  return (unsigned)(q0 & 0xff) | ((unsigned)(q1 & 0xff) << 8) |
         ((unsigned)(q2 & 0xff) << 16) | ((unsigned)(q3 & 0xff) << 24);
}

// ---------------- zero deg + stats ----------------
__global__ __launch_bounds__(256) void zero_kernel(int* __restrict__ deg,
                                                   float* __restrict__ stats, int n) {
  int i = blockIdx.x * 256 + threadIdx.x;
  if (i < n) deg[i] = 0;
  if (i < 768) stats[i] = 0.f;
}

// ---------------- fused: edge count+rank (4/thread) | x->bf16+int8 | W packs ----------------
// blocks [0,cb4): count. [cb4,cb4+nxq): x rows. [..+48): layer W. [..+4): head W.
__global__ __launch_bounds__(256) void convert_kernel(
    const int* __restrict__ dst, int* __restrict__ deg, int* __restrict__ rank, int e, int cb4,
    const float* __restrict__ x, const float* __restrict__ w1l, const float* __restrict__ w1r,
    const float* __restrict__ w2l, const float* __restrict__ w2r,
    const float* __restrict__ w3l, const float* __restrict__ w3r,
    const float* __restrict__ wh,
    unsigned short* __restrict__ x_bf, unsigned* __restrict__ xi8,
    float* __restrict__ xsc,
    unsigned short* __restrict__ wc1,
    unsigned short* __restrict__ wc2, unsigned short* __restrict__ wc3,
    unsigned short* __restrict__ whb, int n, int nxq) {
  int b = blockIdx.x;
  int t = threadIdx.x;
  if (b < cb4) {
    int i = (b * 256 + t) * 4;
    if (i + 4 <= e) {
      int d0 = dst[i], d1 = dst[i + 1], d2 = dst[i + 2], d3 = dst[i + 3];
      int r0 = atomicAdd(&deg[d0], 1);
      int r1 = atomicAdd(&deg[d1], 1);
      int r2 = atomicAdd(&deg[d2], 1);
      int r3 = atomicAdd(&deg[d3], 1);
      rank[i] = r0; rank[i + 1] = r1; rank[i + 2] = r2; rank[i + 3] = r3;
    } else {
      for (int k = i; k < e; k++) rank[k] = atomicAdd(&deg[dst[k]], 1);
    }
    return;
  }
  int r0 = b - cb4;
  if (r0 < nxq) {
    int row = r0 * 8 + (t >> 5);
    int lane = t & 31;
    if (row >= n) return;
    float4 a = *reinterpret_cast<const float4*>(x + (size_t)row * FC + lane * 4);
    ushort4 o = {f2bf(a.x), f2bf(a.y), f2bf(a.z), f2bf(a.w)};
    *reinterpret_cast<ushort4*>(x_bf + (size_t)row * FC + lane * 4) = o;
    float m = fmaxf(fmaxf(fabsf(a.x), fabsf(a.y)), fmaxf(fabsf(a.z), fabsf(a.w)));
    m = fmaxf(m, __shfl_xor(m, 1));
    m = fmaxf(m, __shfl_xor(m, 2));
    m = fmaxf(m, __shfl_xor(m, 4));
    m = fmaxf(m, __shfl_xor(m, 8));
    m = fmaxf(m, __shfl_xor(m, 16));
    float inv = 127.0f / fmaxf(m, 1e-30f);
    int q0 = (int)rintf(a.x * inv), q1 = (int)rintf(a.y * inv);
    int q2 = (int)rintf(a.z * inv), q3 = (int)rintf(a.w * inv);
    xi8[(size_t)row * 32 + lane] = pk_i8x4(q0, q1, q2, q3);
    if (lane == 0) xsc[row] = m * (1.0f / 127.0f);
    return;
  }
  int r = r0 - nxq;
  if (r < 48) {
    int layer = r >> 4;
    const float* wl = layer == 0 ? w1l : (layer == 1 ? w2l : w3l);
    const float* wr = layer == 0 ? w1r : (layer == 1 ? w2r : w3r);
    unsigned short* out = layer == 0 ? wc1 : (layer == 1 ? wc2 : wc3);
    int i = (r & 15) * 256 + t;   // 0..4095
    int row = i >> 5;
    int k8 = (i & 31) * 8;
    const float* src = (k8 < 128) ? (wl + (size_t)row * 128 + k8)
                                  : (wr + (size_t)row * 128 + (k8 - 128));
    float4 a = *reinterpret_cast<const float4*>(src);
    float4 c = *reinterpret_cast<const float4*>(src + 4);
    ushort4 o0 = {f2bf(a.x), f2bf(a.y), f2bf(a.z), f2bf(a.w)};
    ushort4 o1 = {f2bf(c.x), f2bf(c.y), f2bf(c.z), f2bf(c.w)};
    unsigned short* q = out + (size_t)row * 256 + k8;
    *reinterpret_cast<ushort4*>(q) = o0;
    *reinterpret_cast<ushort4*>(q + 4) = o1;
  } else {
    int i = (r - 48) * 256 + t;   // 0..1023
    const float* p = wh + (size_t)i * 8;
    float4 a = *reinterpret_cast<const float4*>(p);
    float4 c = *reinterpret_cast<const float4*>(p + 4);
    ushort4 o0 = {f2bf(a.x), f2bf(a.y), f2bf(a.z), f2bf(a.w)};
    ushort4 o1 = {f2bf(c.x), f2bf(c.y), f2bf(c.z), f2bf(c.w)};
    unsigned short* q = whb + (size_t)i * 8;
    *reinterpret_cast<ushort4*>(q) = o0;
    *reinterpret_cast<ushort4*>(q + 4) = o1;
  }
}

// ---------------- CSR scans + fill ----------------
__global__ __launch_bounds__(256) void scan1_kernel(const int* __restrict__ deg,
                                                    int* __restrict__ bsum, int n) {
  int i = blockIdx.x * 256 + threadIdx.x;
  int v = (i < n) ? deg[i] : 0;
  __shared__ int ls[256];
  ls[threadIdx.x] = v;
  __syncthreads();
  for (int d = 128; d > 0; d >>= 1) {
    if (threadIdx.x < (unsigned)d) ls[threadIdx.x] += ls[threadIdx.x + d];
    __syncthreads();
  }
  if (threadIdx.x == 0) bsum[blockIdx.x] = ls[0];
}

__global__ __launch_bounds__(256) void scan23_kernel(const int* __restrict__ deg,
                                                     const int* __restrict__ bsum,
                                                     int* __restrict__ off, int n, int nb) {
  __shared__ int bls[256];
  __shared__ int ls[256];
  int t = threadIdx.x;
  int bv = (t < nb) ? bsum[t] : 0;
  bls[t] = bv;
  __syncthreads();
  for (int d = 1; d < 256; d <<= 1) {
    int u = (t >= d) ? bls[t - d] : 0;
    __syncthreads();
    bls[t] += u;
    __syncthreads();
  }
  int i = blockIdx.x * 256 + t;
  int v = (i < n) ? deg[i] : 0;
  ls[t] = v;
  __syncthreads();
  for (int d = 1; d < 256; d <<= 1) {
    int u = (t >= d) ? ls[t - d] : 0;
    __syncthreads();
    ls[t] += u;
    __syncthreads();
  }
  int base = blockIdx.x ? bls[blockIdx.x - 1] : 0;
  if (i < n) off[i] = base + ls[t] - v;
  if (blockIdx.x == 0 && t == 0) off[n] = bls[nb - 1];
}

__global__ void fill_kernel(const int* __restrict__ src, const int* __restrict__ dst,
                            const int* __restrict__ rank, const int* __restrict__ off,
                            int* __restrict__ csr, int e) {
  int i = blockIdx.x * blockDim.x + threadIdx.x;
  if (i < e) csr[off[dst[i]] + rank[i]] = src[i];
}

// ---------------- mean aggregation: int8 rows + per-row scale, BN+ReLU on read ----------------
template <bool BNIN>
__global__ __launch_bounds__(256) void aggregate_kernel(const unsigned* __restrict__ xi8,
                                                        const float* __restrict__ xsc,
                                                        const int* __restrict__ off,
                                                        const int* __restrict__ csr,
                                                        unsigned short* __restrict__ agg,
                                                        const float* __restrict__ stats,
                                                        const float* __restrict__ g,
                                                        const float* __restrict__ be,
                                                        float invn, int n) {
  int hw = (int)((blockIdx.x * blockDim.x + threadIdx.x) >> 5);
  int lane = threadIdx.x & 31;
  if (hw >= n) return;

  float sc0 = 1.f, sc1 = 1.f, sc2 = 1.f, sc3 = 1.f;
  float sh0 = 0.f, sh1 = 0.f, sh2 = 0.f, sh3 = 0.f;
  if (BNIN) {
    int c0 = lane * 4;
    float4 s  = *reinterpret_cast<const float4*>(stats + c0);
    float4 s2 = *reinterpret_cast<const float4*>(stats + 128 + c0);
    float4 gv = *reinterpret_cast<const float4*>(g + c0);
    float4 bv = *reinterpret_cast<const float4*>(be + c0);
    float m0 = s.x * invn, m1 = s.y * invn, m2 = s.z * invn, m3 = s.w * invn;
    sc0 = gv.x * rsqrtf(fmaxf(s2.x * invn - m0 * m0, 0.f) + 1e-5f);
    sc1 = gv.y * rsqrtf(fmaxf(s2.y * invn - m1 * m1, 0.f) + 1e-5f);
    sc2 = gv.z * rsqrtf(fmaxf(s2.z * invn - m2 * m2, 0.f) + 1e-5f);
    sc3 = gv.w * rsqrtf(fmaxf(s2.w * invn - m3 * m3, 0.f) + 1e-5f);
    sh0 = bv.x - m0 * sc0; sh1 = bv.y - m1 * sc1;
    sh2 = bv.z - m2 * sc2; sh3 = bv.w - m3 * sc3;
  }

  int s0 = off[hw], s1 = off[hw + 1];
  float a0 = 0.f, a1 = 0.f, a2 = 0.f, a3 = 0.f;

#define ACCV(u, sv)                                               \
  {                                                               \
    float q0 = (float)(((int)(u) << 24) >> 24);                   \
    float q1 = (float)(((int)(u) << 16) >> 24);                   \
    float q2 = (float)(((int)(u) << 8) >> 24);                    \
    float q3 = (float)((int)(u) >> 24);                           \
    if (BNIN) {                                                   \
      a0 += fmaxf(fmaf(q0, (sv) * sc0, sh0), 0.f);                \
      a1 += fmaxf(fmaf(q1, (sv) * sc1, sh1), 0.f);                \
      a2 += fmaxf(fmaf(q2, (sv) * sc2, sh2), 0.f);                \
      a3 += fmaxf(fmaf(q3, (sv) * sc3, sh3), 0.f);                \
    } else {                                                      \
      a0 = fmaf(q0, (sv), a0);                                    \
      a1 = fmaf(q1, (sv), a1);                                    \
      a2 = fmaf(q2, (sv), a2);                                    \
      a3 = fmaf(q3, (sv), a3);                                    \
    }                                                             \
  }

  int j = s0;
  for (; j + 8 <= s1; j += 8) {
    int i0 = csr[j],     i1 = csr[j + 1], i2 = csr[j + 2], i3 = csr[j + 3];
    int i4 = csr[j + 4], i5 = csr[j + 5], i6 = csr[j + 6], i7 = csr[j + 7];
    unsigned u0 = xi8[(size_t)i0 * 32 + lane];
    unsigned u1 = xi8[(size_t)i1 * 32 + lane];
    unsigned u2 = xi8[(size_t)i2 * 32 + lane];
    unsigned u3 = xi8[(size_t)i3 * 32 + lane];
    unsigned u4 = xi8[(size_t)i4 * 32 + lane];
    unsigned u5 = xi8[(size_t)i5 * 32 + lane];
    unsigned u6 = xi8[(size_t)i6 * 32 + lane];
    unsigned u7 = xi8[(size_t)i7 * 32 + lane];
    float sv0 = xsc[i0], sv1 = xsc[i1], sv2 = xsc[i2], sv3 = xsc[i3];
    float sv4 = xsc[i4], sv5 = xsc[i5], sv6 = xsc[i6], sv7 = xsc[i7];
    ACCV(u0, sv0) ACCV(u1, sv1) ACCV(u2, sv2) ACCV(u3, sv3)
    ACCV(u4, sv4) ACCV(u5, sv5) ACCV(u6, sv6) ACCV(u7, sv7)
  }
  for (; j < s1; j++) {
    int i0 = csr[j];
    unsigned u0 = xi8[(size_t)i0 * 32 + lane];
    float sv0 = xsc[i0];
    ACCV(u0, sv0)
  }
#undef ACCV

  int d = s1 - s0;
  float inv = 1.0f / (float)(d > 0 ? d : 1);
  ushort4 o = {f2bf(a0 * inv), f2bf(a1 * inv), f2bf(a2 * inv), f2bf(a3 * inv)};
  *reinterpret_cast<ushort4*>(agg + (size_t)hw * FC + lane * 4) = o;
}

// ---------------- MFMA GEMM: W in LDS (XOR-swizzled), A preloaded ----------------
template <int NCOLS, int KTOT, bool DUAL, bool OUT_BF, bool STATS, bool BNIN, bool OUT_I8>
__global__ __launch_bounds__(256) void gemm_kernel(const unsigned short* __restrict__ A1,
                                                   const unsigned short* __restrict__ A2,
                                                   const unsigned short* __restrict__ W,
                                                   const float* __restrict__ bias,
                                                   void* __restrict__ Cout,
                                                   unsigned char* __restrict__ h8,
                                                   float* __restrict__ hsc,
                                                   float* __restrict__ statsOut,
                                                   const float* __restrict__ statsIn,
                                                   const float* __restrict__ g,
                                                   const float* __restrict__ be,
                                                   float invn, int nrows) {
  constexpr int NKT = KTOT / 32;
  constexpr int NCF = NCOLS / 16;
  constexpr int RB = KTOT * 2;
  constexpr int WBYTES = NCOLS * KTOT * 2;
  __shared__ __align__(16) unsigned char Wl[WBYTES];
  __shared__ float scv[128], shv[128];

  int t = threadIdx.x;

  {
    constexpr int CH = WBYTES / 16 / 256;
#pragma unroll
    for (int c = 0; c < CH; c++) {
      int byte = (c * 256 + t) * 16;
      int row = byte / RB;
      int cb = byte % RB;
      float4 v = *reinterpret_cast<const float4*>(reinterpret_cast<const char*>(W) + byte);
      *reinterpret_cast<float4*>(Wl + row * RB + (cb ^ ((row & 7) << 4))) = v;
    }
  }

  if (BNIN && t < 128) {
    float mean = statsIn[t] * invn;
    float var = fmaxf(statsIn[128 + t] * invn - mean * mean, 0.f);
    float s = g[t] * rsqrtf(var + 1e-5f);
    scv[t] = s;
    shv[t] = be[t] - mean * s;
  }

  int w = t >> 6;
  int l = t & 63;
  int lm = l & 15;
  int hi = l >> 4;
  int lk = hi * 8;
  int row = blockIdx.x * 64 + w * 16 + lm;
  int rclamp = min(row, nrows - 1);

  bf16x8 a[NKT];
#pragma unroll
  for (int kt = 0; kt < NKT; kt++) {
    const unsigned short* Ap;
    int kk;
    if (!DUAL || kt < NKT / 2) { Ap = A1; kk = kt * 32; }
    else                       { Ap = A2; kk = (kt - NKT / 2) * 32; }
    a[kt] = *reinterpret_cast<const bf16x8*>(Ap + (size_t)rclamp * 128 + kk + lk);
  }

  f32x4 acc[NCF];
#pragma unroll
  for (int cf = 0; cf < NCF; cf++) acc[cf] = {0.f, 0.f, 0.f, 0.f};

  __syncthreads();

  if (BNIN) {
#pragma unroll
    for (int kt = 0; kt < NKT; kt++) {
      if (!DUAL || kt >= NKT / 2) {
        int ch0 = (DUAL ? (kt - NKT / 2) : kt) * 32 + lk;
#pragma unroll
        for (int j = 0; j < 8; j++) {
          float v = (float)a[kt][j];
          v = fmaxf(fmaf(v, scv[ch0 + j], shv[ch0 + j]), 0.f);
          a[kt][j] = (__bf16)v;
        }
      }
    }
  }

#pragma unroll
  for (int kt = 0; kt < NKT; kt++) {
#pragma unroll
    for (int cf = 0; cf < NCF; cf++) {
      int r = cf * 16 + lm;
      int cb = kt * 64 + hi * 16;
      bf16x8 b = *reinterpret_cast<const bf16x8*>(Wl + r * RB + (cb ^ ((r & 7) << 4)));
      acc[cf] = __builtin_amdgcn_mfma_f32_16x16x32_bf16(a[kt], b, acc[cf], 0, 0, 0);
    }
  }

  // fold bias in-place
#pragma unroll
  for (int cf = 0; cf < NCF; cf++) {
    float bs = bias[cf * 16 + lm];
#pragma unroll
    for (int r = 0; r < 4; r++) acc[cf][r] += bs;
  }

  // per-output-row scale for int8
  float qinv[4], qs[4];
  if (OUT_I8) {
#pragma unroll
    for (int r = 0; r < 4; r++) {
      float m = 0.f;
#pragma unroll
      for (int cf = 0; cf < NCF; cf++) m = fmaxf(m, fabsf(acc[cf][r]));
      m = fmaxf(m, __shfl_xor(m, 1));
      m = fmaxf(m, __shfl_xor(m, 2));
      m = fmaxf(m, __shfl_xor(m, 4));
      m = fmaxf(m, __shfl_xor(m, 8));
      qinv[r] = 127.0f / fmaxf(m, 1e-30f);
      qs[r] = m * (1.0f / 127.0f);
    }
  }

  __shared__ float wsum[4][NCOLS];
  __shared__ float wsq[4][NCOLS];

  int orow0 = blockIdx.x * 64 + w * 16 + hi * 4;
#pragma unroll
  for (int cf = 0; cf < NCF; cf++) {
    int col = cf * 16 + lm;
    float s = 0.f, s2 = 0.f;
#pragma unroll
    for (int r = 0; r < 4; r++) {
      int orow = orow0 + r;
      bool ok = orow < nrows;
      float v = acc[cf][r];
      if (ok) {
        if (OUT_BF)
          ((unsigned short*)Cout)[(size_t)orow * NCOLS + col] = f2bf(v);
        else
          ((float*)Cout)[(size_t)orow * NCOLS + col] = v;
        if (OUT_I8)
          h8[(size_t)orow * NCOLS + col] = (unsigned char)((int)rintf(v * qinv[r]) & 0xff);
      }
      if (STATS) {
        float vv = ok ? v : 0.f;
        s += vv; s2 += vv * vv;
      }
    }
    if (STATS) {
      s  += __shfl_xor(s, 16);  s  += __shfl_xor(s, 32);
      s2 += __shfl_xor(s2, 16); s2 += __shfl_xor(s2, 32);
      if (l < 16) { wsum[w][col] = s; wsq[w][col] = s2; }
    }
  }
  if (OUT_I8 && lm == 0) {
#pragma unroll
    for (int r = 0; r < 4; r++) {
      int orow = orow0 + r;
      if (orow < nrows) hsc[orow] = qs[r];
    }
  }
  if (STATS) {
    __syncthreads();
    if (t < NCOLS) {
      atomicAdd(&statsOut[t], wsum[0][t] + wsum[1][t] + wsum[2][t] + wsum[3][t]);
    } else if (t < 2 * NCOLS) {
      int c = t - NCOLS;
      atomicAdd(&statsOut[t], wsq[0][c] + wsq[1][c] + wsq[2][c] + wsq[3][c]);
    }
  }
}

// ---------------- launch ----------------
extern "C" void kernel_launch(void* const* d_in, const int* in_sizes, int n_in,
                              void* d_out, int out_size, void* d_ws, size_t ws_size,
                              hipStream_t stream) {
  const float* x   = (const float*)d_in[0];
  const int*   ei  = (const int*)d_in[1];
  const float* w1l = (const float*)d_in[2];
  const float* w1r = (const float*)d_in[3];
  const float* b1c = (const float*)d_in[4];
  const float* w2l = (const float*)d_in[5];
  const float* w2r = (const float*)d_in[6];
  const float* b2c = (const float*)d_in[7];
  const float* w3l = (const float*)d_in[8];
  const float* w3r = (const float*)d_in[9];
  const float* b3c = (const float*)d_in[10];
  const float* g1  = (const float*)d_in[11];
  const float* be1 = (const float*)d_in[12];
  const float* g2  = (const float*)d_in[13];
  const float* be2 = (const float*)d_in[14];
  const float* g3  = (const float*)d_in[15];
  const float* be3 = (const float*)d_in[16];
  const float* wh  = (const float*)d_in[17];
  const float* bh  = (const float*)d_in[18];

  int n = in_sizes[0] / FC;
  int e = in_sizes[1] / 2;
  const int* srcI = ei;
  const int* dstI = ei + e;

  char* p = (char*)d_ws;
  auto take = [&](size_t bytes) {
    char* q = p;
    p += (bytes + 255) & ~(size_t)255;
    return q;
  };
  int nb = (n + 255) / 256;
  int cb = (e + 255) / 256;
  int cb4 = (e + 1023) / 1024;
  int nxq = (n + 7) / 8;
  int gb = (n + 63) / 64;
  int ab = (n + 7) / 8;

  int* deg  = (int*)take((size_t)n * 4);
  int* off  = (int*)take((size_t)(n + 1) * 4);
  int* bsum = (int*)take((size_t)nb * 4);
  int* rank = (int*)take((size_t)e * 4);
  int* csr  = (int*)take((size_t)e * 4);
  unsigned short* x_bf = (unsigned short*)take((size_t)n * FC * 2);
  unsigned short* agg  = (unsigned short*)take((size_t)n * FC * 2);
  unsigned short* h1   = (unsigned short*)take((size_t)n * FC * 2);
  unsigned short* h2   = (unsigned short*)take((size_t)n * FC * 2);
  unsigned char*  ai8  = (unsigned char*)take((size_t)n * FC);
  float*          asc  = (float*)take((size_t)n * 4);
  unsigned short* wc1  = (unsigned short*)take(128 * 256 * 2);
  unsigned short* wc2  = (unsigned short*)take(128 * 256 * 2);
  unsigned short* wc3  = (unsigned short*)take(128 * 256 * 2);
  unsigned short* whb  = (unsigned short*)take(64 * 128 * 2);
  float* stats = (float*)take(3 * 256 * 4);

  float invn = 1.0f / (float)n;

  zero_kernel<<<nb, 256, 0, stream>>>(deg, stats, n);
  convert_kernel<<<cb4 + nxq + 52, 256, 0, stream>>>(
      dstI, deg, rank, e, cb4, x, w1l, w1r, w2l, w2r, w3l, w3r, wh,
      x_bf, (unsigned*)ai8, asc, wc1, wc2, wc3, whb, n, nxq);

  scan1_kernel<<<nb, 256, 0, stream>>>(deg, bsum, n);
  scan23_kernel<<<nb, 256, 0, stream>>>(deg, bsum, off, n, nb);
  fill_kernel<<<cb, 256, 0, stream>>>(srcI, dstI, rank, off, csr, e);

  // layer 1: gather int8(x); root = bf16 x; emit h1 bf16 + int8 into ai8/asc
  aggregate_kernel<false><<<ab, 256, 0, stream>>>((const unsigned*)ai8, asc, off, csr, agg,
                                                  nullptr, nullptr, nullptr, invn, n);
  gemm_kernel<128, 256, true, true, true, false, true><<<gb, 256, 0, stream>>>(
      agg, x_bf, wc1, b1c, h1, ai8, asc, stats, nullptr, nullptr, nullptr, invn, n);

  // layer 2: gather int8(h1) with BN1 on read; root = bf16 h1 (BN1 in gemm)
  aggregate_kernel<true><<<ab, 256, 0, stream>>>((const unsigned*)ai8, asc, off, csr, agg,
                                                 stats, g1, be1, invn, n);
  gemm_kernel<128, 256, true, true, true, true, true><<<gb, 256, 0, stream>>>(
      agg, h1, wc2, b2c, h2, ai8, asc, stats + 256, stats, g1, be1, invn, n);

  // layer 3: gather int8(h2) with BN2 on read; no int8 out (head reads bf16)
  aggregate_kernel<true><<<ab, 256, 0, stream>>>((const unsigned*)ai8, asc, off, csr, agg,
                                                 stats + 256, g2, be2, invn, n);
  gemm_kernel<128, 256, true, true, true, true, false><<<gb, 256, 0, stream>>>(
      agg, h2, wc3, b3c, h1, nullptr, nullptr, stats + 512, stats + 256, g2, be2, invn, n);

  // head: BN3 on read of h1
  gemm_kernel<64, 128, false, false, false, true, false><<<gb, 256, 0, stream>>>(
      h1, nullptr, whb, bh, d_out, nullptr, nullptr, nullptr, stats + 512, g3, be3, invn, n);
}